// Round 5
// baseline (16707.796 us; speedup 1.0000x reference)
//
#include <hip/hip_runtime.h>
#include <hip/hip_bf16.h>
#include <type_traits>

// ---------------------------------------------------------------------------
// Seq2SeqAttention R9: tree barrier + pre-packed x.
//   R8 post-mortem: per-step 15.3us = L2 volume (~4.6us, structural) +
//   split8-on-x VALU (~2.6us, redundant 512x) + flat 256-way same-line
//   atomic arrival at IC (up to ~5us serialization) + latency.
//   R9: (1) 2-level barrier: 16 leaves (bx&15, 128B-spaced) + root ->
//   serialized depth 256 -> ~32. (2) one-time in-place pack of input_seq
//   fp32 -> (bf16hi | bf16lo<<16) u32; encoder unpacks with and/shift
//   (bit-identical hi/lo, ~4x fewer VALU ops, no float re-rounding).
//   Everything else identical to R8.
// MFMA 16x16x32 bf16 layouts (m89/m91-verified): A[m=lane&15][k=quad*8+j],
// B[k=quad*8+j][n=lane&15], D col=lane&15 row=quad*4+reg.
// ---------------------------------------------------------------------------

static constexpr int T_ = 512, B_ = 128, I_ = 256, H_ = 1024, O_ = 256;

typedef unsigned short ushort;
typedef unsigned long long u64;
typedef __attribute__((ext_vector_type(8))) short bf16x8;
typedef __attribute__((ext_vector_type(4))) float f32x4;
typedef __attribute__((ext_vector_type(4))) unsigned uint4_t;
typedef __attribute__((ext_vector_type(8))) _Float16 half8;

__device__ __forceinline__ float bf2f(ushort u) {
    union { unsigned i; float f; } cv; cv.i = ((unsigned)u) << 16; return cv.f;
}
__device__ __forceinline__ ushort f2bf(float f) {   // RNE
    union { float f; unsigned u; } c; c.f = f;
    unsigned r = c.u + 0x7FFFu + ((c.u >> 16) & 1u);
    return (ushort)(r >> 16);
}
__device__ __forceinline__ float fast_sigmoid(float x) { return 1.f / (1.f + __expf(-x)); }
__device__ __forceinline__ float fast_tanh(float x) {
    float ax = fabsf(x);
    float e = __expf(-2.f * ax);
    float t = (1.f - e) / (1.f + e);
    return copysignf(t, x);
}
__device__ __forceinline__ f32x4 mfma16(bf16x8 a, bf16x8 b, f32x4 c) {
    return __builtin_amdgcn_mfma_f32_16x16x32_bf16(a, b, c, 0, 0, 0);
}
__device__ __forceinline__ bf16x8 ld8(const ushort* p) { return *(const bf16x8*)(const void*)p; }

// ---- panel-layout fragment loads -------------------------------------------
// h-like buffer [B_=128][H] as [t][chunk=h>>2][b][4]; row = t*128+b.
__device__ __forceinline__ bf16x8 ld8p(const ushort* base, int row, int ko) {
    const size_t t = (size_t)(row >> 7);
    const int b = row & 127;
    const ushort* p0 = base + t * (size_t)(B_ * H_) + ((size_t)((ko >> 2) * B_ + b) << 2);
    union { u64 q[2]; bf16x8 v; } u;
    u.q[0] = *(const u64*)(const void*)p0;
    u.q[1] = *(const u64*)(const void*)(p0 + (B_ << 2));
    return u.v;
}

// ---- split 8 fp32 into bf16 hi/lo fragments --------------------------------
__device__ __forceinline__ void split8(const float* p, bf16x8& hi, bf16x8& lo) {
    #pragma unroll
    for (int j = 0; j < 8; j++) {
        const float f = p[j];
        const ushort h = f2bf(f);
        hi[j] = (short)h;
        lo[j] = (short)f2bf(f - bf2f(h));
    }
}

// ---- weight split pre-pass -------------------------------------------------
__global__ __launch_bounds__(256) void split_w(
    const float* __restrict__ src, int srcld, int coloff,
    ushort* __restrict__ hi, ushort* __restrict__ lo, int K)
{
    const int k = blockIdx.x * 256 + threadIdx.x;
    const int r = blockIdx.y;
    const float f = src[(size_t)r * srcld + coloff + k];
    const ushort h = f2bf(f);
    hi[(size_t)r * K + k] = h;
    lo[(size_t)r * K + k] = f2bf(f - bf2f(h));
}

// ---- in-place x pack: fp32 -> (bf16hi | bf16lo<<16), same addresses --------
__global__ __launch_bounds__(256) void pack_x(float* __restrict__ x)
{
    const size_t i = ((size_t)blockIdx.x * 256 + threadIdx.x) * 8;
    float4 a = *(const float4*)(x + i);
    float4 b = *(const float4*)(x + i + 4);
    unsigned w[8];
    const float f_[8] = {a.x, a.y, a.z, a.w, b.x, b.y, b.z, b.w};
    #pragma unroll
    for (int j = 0; j < 8; j++) {
        const ushort h = f2bf(f_[j]);
        const ushort l = f2bf(f_[j] - bf2f(h));
        w[j] = (unsigned)h | ((unsigned)l << 16);
    }
    *(uint4_t*)(void*)(x + i)     = uint4_t{w[0], w[1], w[2], w[3]};
    *(uint4_t*)(void*)(x + i + 4) = uint4_t{w[4], w[5], w[6], w[7]};
}

// ---------------------------------------------------------------------------
// Persistent encoder: 256 blocks (1/CU), 512 threads (8 waves). Block owns
// 4 h-values (16 gate-cols) x all 128 batch rows; wave w = row-tile w*16.
// LDS: Whh hi/lo [32][64][8] + Wih hi/lo [8][64][8] + Gt[16][132].
// hi: ctx_seq history (plain virgin loads). lo: 256-slot virgin ring.
// Barrier: 2-level tree (16 leaves + root), fence-free, monotonic.
// ---------------------------------------------------------------------------
#define ENC_SMEM_BYTES (32*64*8*2*2 + 8*64*8*2*2 + 16*132*4)   // 90368
#define LORING_SLOTS 256
// barbuf layout (u32 idx): [0]=release, [32]=root, [64+g*16]=leaf g (g<16)

__global__ __launch_bounds__(512) void enc_persistent(
    const unsigned* __restrict__ xpk,             // packed x [t][b][k] u32
    const ushort* __restrict__ WhhE_h, const ushort* __restrict__ WhhE_l,
    const ushort* __restrict__ WihE_h, const ushort* __restrict__ WihE_l,
    const float* __restrict__ bih, const float* __restrict__ bhh,
    const ushort* __restrict__ hzero,
    ushort* __restrict__ ctx_seq,                 // panel [t][c][b][4], hi history
    ushort* __restrict__ loring,                  // panel ring [256][c][b][4]
    ushort* __restrict__ enc_lo_fin,              // final lo (survives P-GEMM)
    unsigned* __restrict__ bar)
{
    extern __shared__ __align__(16) char smem[];
    ushort* LWh = (ushort*)smem;                 // Whh hi  [32][64][8]
    ushort* LWl = LWh + 32 * 64 * 8;             // Whh lo
    ushort* LIh = LWl + 32 * 64 * 8;             // Wih hi  [8][64][8]
    ushort* LIl = LIh + 8 * 64 * 8;              // Wih lo
    float*  Gt  = (float*)(LIl + 8 * 64 * 8);    // [16 cols][132]

    const int tid  = threadIdx.x;
    const int wave = tid >> 6, lane = tid & 63;
    const int quad = lane >> 4, l15 = lane & 15;
    const int bx   = blockIdx.x;
    const int h0   = bx << 2;
    const int wr   = ((l15 >> 2) * H_) + h0 + (l15 & 3);   // gate*H + h row of W

    // ---- stage weights into LDS (lane-major fragments; done once) ----
    {
        const size_t woff = (size_t)wr * H_;
        #pragma unroll
        for (int ii = 0; ii < 4; ii++) {
            const int i   = wave + (ii << 3);          // K-iter index 0..31
            const int src = (i << 5) + (quad << 3);
            *(bf16x8*)(LWh + ((i << 6) + lane) * 8) = ld8(WhhE_h + woff + src);
            *(bf16x8*)(LWl + ((i << 6) + lane) * 8) = ld8(WhhE_l + woff + src);
        }
        const size_t ioff = (size_t)wr * I_;
        const int src2 = (wave << 5) + (quad << 3);    // K-iter index = wave (0..7)
        *(bf16x8*)(LIh + ((wave << 6) + lane) * 8) = ld8(WihE_h + ioff + src2);
        *(bf16x8*)(LIl + ((wave << 6) + lane) * 8) = ld8(WihE_l + ioff + src2);
    }

    // per-thread cell-update mapping + persistent state
    const int bl_  = tid >> 2, hl = tid & 3;
    const int hidx = h0 + hl;
    const float bs0 = bih[hidx]           + bhh[hidx];
    const float bs1 = bih[H_ + hidx]      + bhh[H_ + hidx];
    const float bs2 = bih[2 * H_ + hidx]  + bhh[2 * H_ + hidx];
    const float bs3 = bih[3 * H_ + hidx]  + bhh[3 * H_ + hidx];
    float c_reg = 0.f;
    __syncthreads();

    const int arow = (wave << 4) + l15;   // batch row for MFMA A (0..127)
    const size_t xoff = (size_t)arow * I_;

    for (int t = 0; t < T_; t++) {
        const unsigned* xs = xpk + (size_t)t * (B_ * I_) + xoff;

        f32x4 acc0 = {0.f, 0.f, 0.f, 0.f}, acc1 = acc0, acc2 = acc0;
        // ---- segment 2 FIRST: x @ Wih^T (h-independent; overlaps barrier) --
        #pragma unroll
        for (int kc = 0; kc < I_; kc += 32) {
            const int i = kc >> 5;
            const bf16x8 bh = *(const bf16x8*)(LIh + ((i << 6) + lane) * 8);
            const bf16x8 bl = *(const bf16x8*)(LIl + ((i << 6) + lane) * 8);
            const uint4_t w0 = *(const uint4_t*)(const void*)(xs + kc + (quad << 3));
            const uint4_t w1 = *(const uint4_t*)(const void*)(xs + kc + (quad << 3) + 4);
            bf16x8 ah, al;
            ah[0] = (short)(w0.x & 0xffff); al[0] = (short)(w0.x >> 16);
            ah[1] = (short)(w0.y & 0xffff); al[1] = (short)(w0.y >> 16);
            ah[2] = (short)(w0.z & 0xffff); al[2] = (short)(w0.z >> 16);
            ah[3] = (short)(w0.w & 0xffff); al[3] = (short)(w0.w >> 16);
            ah[4] = (short)(w1.x & 0xffff); al[4] = (short)(w1.x >> 16);
            ah[5] = (short)(w1.y & 0xffff); al[5] = (short)(w1.y >> 16);
            ah[6] = (short)(w1.z & 0xffff); al[6] = (short)(w1.z >> 16);
            ah[7] = (short)(w1.w & 0xffff); al[7] = (short)(w1.w >> 16);
            acc0 = mfma16(ah, bh, acc0);
            acc1 = mfma16(ah, bl, acc1);
            acc2 = mfma16(al, bh, acc2);
        }

        // ---- wait: h_{t-1} published (release of step t) ----
        if (t != 0) {
            if (tid == 0) {
                while (__hip_atomic_load(&bar[0], __ATOMIC_RELAXED,
                                         __HIP_MEMORY_SCOPE_AGENT) < (unsigned)t)
                    __builtin_amdgcn_s_sleep(2);
            }
            __syncthreads();
        }

        // ---- segment 1: h @ Whh^T (weights LDS; hi+lo plain virgin loads) --
        const ushort* hi_src = t ? (ctx_seq + (size_t)(t - 1) * (B_ * H_)) : hzero;
        const ushort* lo_src = t ? (loring + (size_t)((t - 1) & (LORING_SLOTS - 1))
                                             * (B_ * H_)) : hzero;
        #pragma unroll 8
        for (int kc = 0; kc < H_; kc += 32) {
            const int i  = kc >> 5;
            const int ko = kc + (quad << 3);
            const bf16x8 bh = *(const bf16x8*)(LWh + ((i << 6) + lane) * 8);
            const bf16x8 bl = *(const bf16x8*)(LWl + ((i << 6) + lane) * 8);
            const bf16x8 ah = ld8p(hi_src, arow, ko);
            const bf16x8 al = ld8p(lo_src, arow, ko);
            acc0 = mfma16(ah, bh, acc0);
            acc1 = mfma16(ah, bl, acc1);
            acc2 = mfma16(al, bh, acc2);
        }
        // gate exchange: Gt[col][row]; D: row=quad*4+r, col=l15
        #pragma unroll
        for (int r = 0; r < 4; r++)
            Gt[l15 * 132 + (wave << 4) + (quad << 2) + r] = acc0[r] + acc1[r] + acc2[r];
        __syncthreads();

        // cell update (thread -> (batch row bl_, h-local hl)); c in register
        const float gi = Gt[hl * 132 + bl_]        + bs0;
        const float gf = Gt[(4 + hl) * 132 + bl_]  + bs1;
        const float gg = Gt[(8 + hl) * 132 + bl_]  + bs2;
        const float go = Gt[(12 + hl) * 132 + bl_] + bs3;
        const float ig = fast_sigmoid(gi), fg = fast_sigmoid(gf);
        const float gtv = fast_tanh(gg),   og = fast_sigmoid(go);
        c_reg = fg * c_reg + ig * gtv;
        const float hnew = og * fast_tanh(c_reg);
        const ushort hh  = f2bf(hnew);
        const ushort hlo = f2bf(hnew - bf2f(hh));

        // panel stores: thread-linear packed 4B sc1 write-through (IC truth)
        const unsigned hp = (unsigned)hh  | (__shfl_down((unsigned)hh, 1)  << 16);
        const unsigned lp = (unsigned)hlo | (__shfl_down((unsigned)hlo, 1) << 16);
        const unsigned pi = ((unsigned)bx << 9) + (unsigned)tid;
        if (!(tid & 1)) {
            __hip_atomic_store((unsigned*)(void*)&ctx_seq[(size_t)t * (B_ * H_) + pi],
                               hp, __ATOMIC_RELAXED, __HIP_MEMORY_SCOPE_AGENT);
            __hip_atomic_store((unsigned*)(void*)
                               &loring[(size_t)(t & (LORING_SLOTS - 1)) * (B_ * H_) + pi],
                               lp, __ATOMIC_RELAXED, __HIP_MEMORY_SCOPE_AGENT);
            if (t == T_ - 1)   // survives P-GEMM overwriting loring
                *(unsigned*)(void*)&enc_lo_fin[pi] = lp;
        }

        // ---- tree arrival: leaf (bx&15) -> root -> release ----
        if (t != T_ - 1) {
            __syncthreads();   // drains vmcnt: stores IC-visible before arrival
            if (tid == 0) {
                const unsigned tgt = (unsigned)(t + 1) * 16u;
                unsigned* leaf = bar + 64 + ((bx & 15) << 4);   // 64B-spaced
                const unsigned la = __hip_atomic_fetch_add(leaf, 1u, __ATOMIC_RELAXED,
                                                           __HIP_MEMORY_SCOPE_AGENT) + 1;
                if (la == tgt) {
                    const unsigned ra = __hip_atomic_fetch_add(&bar[32], 1u,
                                            __ATOMIC_RELAXED, __HIP_MEMORY_SCOPE_AGENT) + 1;
                    if (ra == tgt)
                        __hip_atomic_store(&bar[0], (unsigned)(t + 1),
                                           __ATOMIC_RELAXED, __HIP_MEMORY_SCOPE_AGENT);
                }
            }
        }
    }
}

// ---- fused LSTM step (decoder). Block: 64 batch rows x 16 gate-cols. -------
// grid (H/4 = 256 colgroups, 2 row-halves). A-side h/x PANEL layout.
template<bool WSPLIT, bool XSPLIT, int KX>
__global__ __launch_bounds__(256) void lstm_mfma(
    const ushort* __restrict__ h_hi, const ushort* __restrict__ h_lo,
    const void* __restrict__ x_p, const ushort* __restrict__ x_lo,
    const void* __restrict__ Whh_a, const void* __restrict__ Whh_b,
    const void* __restrict__ Wih_a, const void* __restrict__ Wih_b,
    const float* __restrict__ bih, const float* __restrict__ bhh,
    const float* __restrict__ c_in, float* __restrict__ c_out,
    ushort* __restrict__ h_out_hi, ushort* __restrict__ h_out_lo)
{
    __shared__ float Gt[16][65];
    const int tid = threadIdx.x;
    const int wave = tid >> 6, lane = tid & 63;
    const int quad = lane >> 4, l15 = lane & 15;
    const int h0 = blockIdx.x << 2;
    const int mbase = (blockIdx.y << 6) + (wave << 4);
    const int arow = mbase + l15;
    const int wr = ((l15 >> 2) * H_) + h0 + (l15 & 3);   // gate*H + h index

    f32x4 acc0 = {0.f,0.f,0.f,0.f}, acc1 = acc0, acc2 = acc0;

    // segment 1: h @ Whh^T, K = 1024, A split (hi+lo), panel A
    {
        const size_t woff = (size_t)wr * H_;
        #pragma unroll 4
        for (int kc = 0; kc < H_; kc += 32) {
            const int ko = kc + quad * 8;
            bf16x8 bh, bl;
            if constexpr (WSPLIT) {
                bh = ld8((const ushort*)Whh_a + woff + ko);
                bl = ld8((const ushort*)Whh_b + woff + ko);
            } else {
                split8((const float*)Whh_a + woff + ko, bh, bl);
            }
            const bf16x8 ah = ld8p(h_hi, arow, ko);
            const bf16x8 al = ld8p(h_lo, arow, ko);
            acc0 = mfma16(ah, bh, acc0);
            acc1 = mfma16(ah, bl, acc1);
            acc2 = mfma16(al, bh, acc2);
        }
    }
    // segment 2: x @ Wih^T, K = KX (x panel when XSPLIT)
    {
        const size_t woff = (size_t)wr * KX;
        #pragma unroll 2
        for (int kc = 0; kc < KX; kc += 32) {
            const int ko = kc + quad * 8;
            bf16x8 bh, bl;
            if constexpr (WSPLIT) {
                bh = ld8((const ushort*)Wih_a + woff + ko);
                bl = ld8((const ushort*)Wih_b + woff + ko);
            } else {
                split8((const float*)Wih_a + woff + ko, bh, bl);
            }
            bf16x8 ah, al;
            if constexpr (XSPLIT) {
                ah = ld8p((const ushort*)x_p, arow, ko);
                al = ld8p(x_lo, arow, ko);
            } else {
                split8((const float*)x_p + (size_t)arow * KX + ko, ah, al);
            }
            acc0 = mfma16(ah, bh, acc0);
            acc1 = mfma16(ah, bl, acc1);
            acc2 = mfma16(al, bh, acc2);
        }
    }
    // gate exchange: Gt[col][local_row]; D: row=quad*4+r, col=l15
    #pragma unroll
    for (int r = 0; r < 4; r++)
        Gt[l15][(wave << 4) + quad * 4 + r] = acc0[r] + acc1[r] + acc2[r];
    __syncthreads();

    // cell update: thread -> (local batch row, h-local)
    const int bl_ = tid >> 2, hl = tid & 3;
    const int b = (blockIdx.y << 6) + bl_;
    const int hidx = h0 + hl;
    const float gi = Gt[hl][bl_]      + bih[hidx]          + bhh[hidx];
    const float gf = Gt[4 + hl][bl_]  + bih[H_ + hidx]     + bhh[H_ + hidx];
    const float gg = Gt[8 + hl][bl_]  + bih[2 * H_ + hidx] + bhh[2 * H_ + hidx];
    const float go = Gt[12 + hl][bl_] + bih[3 * H_ + hidx] + bhh[3 * H_ + hidx];
    const float ig = fast_sigmoid(gi), fg = fast_sigmoid(gf);
    const float gt = fast_tanh(gg),    og = fast_sigmoid(go);
    const float cold = c_in[b * H_ + hidx];
    const float cnew = fg * cold + ig * gt;
    const float hnew = og * fast_tanh(cnew);
    c_out[b * H_ + hidx] = cnew;
    const ushort hh = f2bf(hnew);
    const size_t op = ((size_t)(hidx >> 2) * B_ + b) * 4 + (hidx & 3);   // panel
    h_out_hi[op] = hh;
    h_out_lo[op] = f2bf(hnew - bf2f(hh));
}

// ---- generic MFMA GEMM: C = act(A @ W^T + bias) ----------------------------
// grid (N/(16*NT), M/64). Wave = 1 M-tile(16 rows) x NT N-tiles.
// APANEL: A in panel layout. OM: 0=f32 row-major, 3=split bf16 PANEL out,
// 4=fp16 dual-region row-major (idx<HALF -> out0)
template<bool A_LO, int NT, int OM, bool RELU, int K, bool APANEL>
__global__ __launch_bounds__(256) void gemm_mfma(
    const ushort* __restrict__ Ahi, const ushort* __restrict__ Alo, int lda,
    const ushort* __restrict__ Whi, const ushort* __restrict__ Wlo,
    const float* __restrict__ bias,
    void* __restrict__ out0, void* __restrict__ out1, int ldc)
{
    const int tid = threadIdx.x;
    const int wave = tid >> 6, lane = tid & 63;
    const int quad = lane >> 4, l15 = lane & 15;
    const int colbase = (blockIdx.x * NT) << 4;
    const int row = (blockIdx.y << 6) + (wave << 4) + l15;
    const size_t aoff = (size_t)row * lda;

    f32x4 acc0[NT], acc1[NT], acc2[NT];
    #pragma unroll
    for (int nt = 0; nt < NT; nt++) {
        acc0[nt] = {0.f,0.f,0.f,0.f}; acc1[nt] = acc0[nt]; acc2[nt] = acc0[nt];
    }
    size_t woff[NT];
    #pragma unroll
    for (int nt = 0; nt < NT; nt++)
        woff[nt] = (size_t)(colbase + (nt << 4) + l15) * K;

    #pragma unroll 2
    for (int kc = 0; kc < K; kc += 32) {
        const int ko = kc + quad * 8;
        const bf16x8 ah = APANEL ? ld8p(Ahi, row, ko) : ld8(Ahi + aoff + ko);
        bf16x8 al;
        if (A_LO) al = APANEL ? ld8p(Alo, row, ko) : ld8(Alo + aoff + ko);
        #pragma unroll
        for (int nt = 0; nt < NT; nt++) {
            const bf16x8 bh = ld8(Whi + woff[nt] + ko);
            const bf16x8 bl = ld8(Wlo + woff[nt] + ko);
            acc0[nt] = mfma16(ah, bh, acc0[nt]);
            acc1[nt] = mfma16(ah, bl, acc1[nt]);
            if (A_LO) acc2[nt] = mfma16(al, bh, acc2[nt]);
        }
    }
    const size_t orow0 = ((size_t)blockIdx.y << 6) + (wave << 4) + quad * 4;
    const size_t HALF_IDX = (size_t)32768 * 1024;   // P region boundary
    #pragma unroll
    for (int nt = 0; nt < NT; nt++) {
        const int col = colbase + (nt << 4) + l15;
        const float bv = bias ? bias[col] : 0.f;
        #pragma unroll
        for (int r = 0; r < 4; r++) {
            float v = acc0[nt][r] + acc1[nt][r] + (A_LO ? acc2[nt][r] : 0.f) + bv;
            if (RELU) v = fmaxf(v, 0.f);
            const size_t idx = (orow0 + r) * (size_t)ldc + col;
            if constexpr (OM == 0) {
                ((float*)out0)[idx] = v;
            } else if constexpr (OM == 3) {     // panel bf16 hi/lo
                const size_t idxp = ((size_t)(col >> 2) * B_ + (orow0 + r)) * 4 + (col & 3);
                const ushort h = f2bf(v);
                ((ushort*)out0)[idxp] = h;
                ((ushort*)out1)[idxp] = f2bf(v - bf2f(h));
            } else {   // OM == 4: fp16 dual region, row-major
                if (idx < HALF_IDX) ((_Float16*)out0)[idx] = (_Float16)v;
                else                ((_Float16*)out1)[idx - HALF_IDX] = (_Float16)v;
            }
        }
    }
}

// ---- scores[b][t] = sum_h v[h]*tanh(q[b][h] + P[t][b][h]); P fp16 2-region -
__global__ __launch_bounds__(256) void attn_score_kernel(
    const float* __restrict__ q,
    const _Float16* __restrict__ P0, const _Float16* __restrict__ P1,
    const float* __restrict__ v, float* __restrict__ scores)
{
    const int wave = threadIdx.x >> 6, lane = threadIdx.x & 63;
    const int p = (blockIdx.x << 2) + wave;
    const int t = p >> 7, b = p & 127;
    const size_t base = (size_t)(t * B_ + b) * H_ + (lane << 4);
    const size_t HALF_IDX = (size_t)32768 * 1024;
    const _Float16* pp = (base < HALF_IDX) ? (P0 + base) : (P1 + (base - HALF_IDX));

    const half8 u0 = *(const half8*)(const void*)pp;
    const half8 u1 = *(const half8*)(const void*)(pp + 8);
    float pv[16];
    #pragma unroll
    for (int j = 0; j < 8; j++) { pv[j] = (float)u0[j]; pv[8 + j] = (float)u1[j]; }

    const float* qp = q + b * H_ + (lane << 4);
    const float* vp = v + (lane << 4);
    float sum = 0.f;
    #pragma unroll
    for (int j0 = 0; j0 < 16; j0 += 4) {
        const float4 qv = *(const float4*)(qp + j0);
        const float4 vv = *(const float4*)(vp + j0);
        sum += vv.x * fast_tanh(qv.x + pv[j0 + 0]);
        sum += vv.y * fast_tanh(qv.y + pv[j0 + 1]);
        sum += vv.z * fast_tanh(qv.z + pv[j0 + 2]);
        sum += vv.w * fast_tanh(qv.w + pv[j0 + 3]);
    }
    #pragma unroll
    for (int off = 32; off; off >>= 1) sum += __shfl_down(sum, off);
    if (lane == 0) scores[b * T_ + t] = sum;
}

// ---- softmax over t; reads scores[b][t], writes transposed scT[t][b] -------
__global__ __launch_bounds__(256) void softmax_kernel(
    const float* __restrict__ scores, float* __restrict__ scT)
{
    __shared__ float red[256];
    const int b = blockIdx.x, tid = threadIdx.x;
    const float s0 = scores[b * T_ + tid];
    const float s1 = scores[b * T_ + tid + 256];
    red[tid] = fmaxf(s0, s1);
    __syncthreads();
    for (int off = 128; off; off >>= 1) {
        if (tid < off) red[tid] = fmaxf(red[tid], red[tid + off]);
        __syncthreads();
    }
    const float mx = red[0];
    __syncthreads();
    const float e0 = __expf(s0 - mx), e1 = __expf(s1 - mx);
    red[tid] = e0 + e1;
    __syncthreads();
    for (int off = 128; off; off >>= 1) {
        if (tid < off) red[tid] += red[tid + off];
        __syncthreads();
    }
    const float inv = 1.f / red[0];
    scT[tid * B_ + b] = e0 * inv;
    scT[(tid + 256) * B_ + b] = e1 * inv;
}

// ---- context (panel): ctx_hi/lo[c][b][4] = sum_t scT[t][b]*ctx[t][c][b][4] -
__global__ __launch_bounds__(256) void attn_context_kernel(
    const float* __restrict__ scT, const ushort* __restrict__ ctx,
    ushort* __restrict__ chi, ushort* __restrict__ clo)
{
    const int u = blockIdx.x * 256 + threadIdx.x;   // 32768 threads
    const int c = u >> 7, b = u & 127;
    const ushort* cp = ctx + ((size_t)(c * B_ + b) << 2);
    const float* wp = scT + b;
    float a0 = 0.f, a1 = 0.f, a2 = 0.f, a3 = 0.f;
    #pragma unroll 4
    for (int t = 0; t < T_; t++) {
        const float w = wp[t << 7];
        const u64 raw = *(const u64*)(const void*)(cp + (size_t)t * (B_ * H_));
        a0 += w * bf2f((ushort)raw);
        a1 += w * bf2f((ushort)(raw >> 16));
        a2 += w * bf2f((ushort)(raw >> 32));
        a3 += w * bf2f((ushort)(raw >> 48));
    }
    const size_t i0 = (size_t)(c * B_ + b) << 2;
    const ushort h0 = f2bf(a0), h1 = f2bf(a1), h2 = f2bf(a2), h3 = f2bf(a3);
    const ushort l0 = f2bf(a0 - bf2f(h0)), l1 = f2bf(a1 - bf2f(h1));
    const ushort l2 = f2bf(a2 - bf2f(h2)), l3 = f2bf(a3 - bf2f(h3));
    *(u64*)(void*)&chi[i0] = (u64)h0 | ((u64)h1 << 16) | ((u64)h2 << 32) | ((u64)h3 << 48);
    *(u64*)(void*)&clo[i0] = (u64)l0 | ((u64)l1 << 16) | ((u64)l2 << 32) | ((u64)l3 << 48);
}

// ---------------------------------------------------------------------------
extern "C" void kernel_launch(void* const* d_in, const int* in_sizes, int n_in,
                              void* d_out, int out_size, void* d_ws, size_t ws_size,
                              hipStream_t stream)
{
    const float* input_seq = (const float*)d_in[0];
    const float* W_ih_enc  = (const float*)d_in[1];
    const float* W_hh_enc  = (const float*)d_in[2];
    const float* b_ih_enc  = (const float*)d_in[3];
    const float* b_hh_enc  = (const float*)d_in[4];
    const float* W_attn    = (const float*)d_in[5];
    const float* b_attn    = (const float*)d_in[6];
    const float* v         = (const float*)d_in[7];
    const float* W_ih_dec  = (const float*)d_in[8];
    const float* W_hh_dec  = (const float*)d_in[9];
    const float* b_ih_dec  = (const float*)d_in[10];
    const float* b_hh_dec  = (const float*)d_in[11];
    const float* W_dec     = (const float*)d_in[12];
    const float* b_dec     = (const float*)d_in[13];
    const float* W_out     = (const float*)d_in[14];
    const float* b_out     = (const float*)d_in[15];
    float* out = (float*)d_out;
    const int LEN = out_size / (B_ * O_);   // 30
    const int BH = B_ * H_;

    char* ws = (char*)d_ws;
    size_t off = 0;
    auto aus = [&](size_t n) { ushort* p = (ushort*)(ws + off); off += n * 2; return p; };
    auto af  = [&](size_t n) { float*  p = (float*) (ws + off); off += n * 4; return p; };

    // pre-split weights (hot / MFMA-consumed). Decoder LSTM W split on the fly.
    ushort* WhhE_h = aus((size_t)4*H_*H_); ushort* WhhE_l = aus((size_t)4*H_*H_);
    ushort* WihE_h = aus((size_t)4*H_*I_); ushort* WihE_l = aus((size_t)4*H_*I_);
    ushort* Wh_h   = aus((size_t)H_*H_);   ushort* Wh_l   = aus((size_t)H_*H_);
    ushort* Wc_h   = aus((size_t)H_*H_);   ushort* Wc_l   = aus((size_t)H_*H_);
    ushort* Wdec_h = aus((size_t)H_*H_);   ushort* Wdec_l = aus((size_t)H_*H_);
    ushort* Wout_h = aus((size_t)O_*H_);   ushort* Wout_l = aus((size_t)O_*H_);

    ushort* ctx_seq = aus((size_t)T_ * BH);          // hi history, panel layout
    ushort* hzero   = aus(BH);
    ushort* enc_lo_fin = aus(BH);                    // final lo (post-P-GEMM use)
    ushort* hd_hi0  = aus(BH); ushort* hd_hi1  = aus(BH);
    ushort* hd_lo0  = aus(BH); ushort* hd_lo1  = aus(BH);
    ushort* ctx_hi  = aus(BH); ushort* ctx_lo  = aus(BH);
    ushort* d1_hi   = aus(BH); ushort* d1_lo   = aus(BH);
    float*  cbuf    = af(BH);
    float*  qbuf    = af(BH);
    float*  scores  = af(B_ * T_);
    float*  scT     = af(B_ * T_);
    unsigned* barbuf = (unsigned*)(ws + off); off += 4096;   // tree-barrier state

    // lo ring: 256 slots x 256KB = 67.1 MB. Dead after encoder -> P1 aliases it.
    ushort* loring = aus((size_t)LORING_SLOTS * BH);
    const size_t P_HALF = (size_t)(T_ / 2) * BH * 2;   // 67,108,864 == loring size
    _Float16* P1 = (_Float16*)loring;
    _Float16* P0;
    if (ws_size >= off + P_HALF) {            // spare ws for P0
        P0 = (_Float16*)(ws + off);
    } else {                                   // alias input_seq (dead after enc)
        P0 = (_Float16*)const_cast<float*>(input_seq);
    }

    // ---- weight split pre-pass ----
    auto spl = [&](const float* src, int srcld, int coloff, ushort* hi, ushort* lo,
                   int R, int K) {
        split_w<<<dim3(K / 256, R), 256, 0, stream>>>(src, srcld, coloff, hi, lo, K);
    };
    spl(W_hh_enc, H_,     0,  WhhE_h, WhhE_l, 4 * H_, H_);
    spl(W_ih_enc, I_,     0,  WihE_h, WihE_l, 4 * H_, I_);
    spl(W_attn,   2 * H_, 0,  Wh_h,   Wh_l,   H_,     H_);
    spl(W_attn,   2 * H_, H_, Wc_h,   Wc_l,   H_,     H_);
    spl(W_dec,    H_,     0,  Wdec_h, Wdec_l, H_,     H_);
    spl(W_out,    H_,     0,  Wout_h, Wout_l, O_,     H_);

    // ---- in-place pack of x: fp32 -> (bf16hi | bf16lo<<16) ----
    pack_x<<<(T_ * B_ * I_) / (256 * 8), 256, 0, stream>>>(
        const_cast<float*>(input_seq));

    hipMemsetAsync(hzero,  0, (size_t)BH * 2, stream);   // h_{-1} = lo_{-1} = 0
    hipMemsetAsync(barbuf, 0, 4096, stream);

    // ---- encoder: ONE persistent kernel, 512 steps, tree barrier ----
    enc_persistent<<<dim3(H_ / 4), 512, ENC_SMEM_BYTES, stream>>>(
        (const unsigned*)input_seq, WhhE_h, WhhE_l, WihE_h, WihE_l,
        b_ih_enc, b_hh_enc, hzero, ctx_seq, loring, enc_lo_fin, barbuf);
    // enc final: hi = ctx_seq[511] (panel), lo = enc_lo_fin (panel)

    // ---- P = ctx_seq @ W_c^T + b_attn  (fp16 row-major, dual region;
    //      P1 overwrites loring, P0 may overwrite input_seq — both dead) ----
    gemm_mfma<false, 8, 4, false, H_, true><<<dim3(8, (T_ * B_) / 64), 256, 0, stream>>>(
        ctx_seq, nullptr, H_, Wc_h, Wc_l, b_attn, P0, P1, H_);

    // ---- decoder ----
    hipMemsetAsync(cbuf, 0, (size_t)BH * 4, stream);
    ushort* dhh[2] = {hd_hi0, hd_hi1};
    ushort* dhl[2] = {hd_lo0, hd_lo1};
    for (int s = 0; s < LEN; s++) {
        const ushort* hi_in = (s == 0) ? ctx_seq + (size_t)(T_ - 1) * BH : dhh[s & 1];
        const ushort* lo_in = (s == 0) ? enc_lo_fin : dhl[s & 1];

        // q = h @ W_h^T (bias folded into P)
        gemm_mfma<true, 1, 0, false, H_, true><<<dim3(H_ / 16, 2), 256, 0, stream>>>(
            hi_in, lo_in, H_, Wh_h, Wh_l, nullptr, qbuf, nullptr, H_);
        attn_score_kernel<<<T_ * B_ / 4, 256, 0, stream>>>(qbuf, P0, P1, v, scores);
        softmax_kernel<<<B_, 256, 0, stream>>>(scores, scT);
        attn_context_kernel<<<BH / 4 / 256, 256, 0, stream>>>(scT, ctx_seq, ctx_hi, ctx_lo);
        // decoder LSTM cell (x = context panel; weights split on the fly)
        lstm_mfma<false, true, H_><<<dim3(H_ / 4, 2), 256, 0, stream>>>(
            hi_in, lo_in, (const void*)ctx_hi, ctx_lo,
            W_hh_dec, nullptr, W_ih_dec, nullptr, b_ih_dec, b_hh_dec,
            cbuf, cbuf, dhh[(s + 1) & 1], dhl[(s + 1) & 1]);
        // d1 = relu(h @ W_dec^T + b_dec) -> split (panel out)
        gemm_mfma<true, 1, 3, true, H_, true><<<dim3(H_ / 16, 2), 256, 0, stream>>>(
            dhh[(s + 1) & 1], dhl[(s + 1) & 1], H_, Wdec_h, Wdec_l, b_dec,
            d1_hi, d1_lo, H_);
        // out = d1 @ W_out^T + b_out  (fp32 row-major final output)
        gemm_mfma<true, 1, 0, false, H_, true><<<dim3(O_ / 16, 2), 256, 0, stream>>>(
            d1_hi, d1_lo, H_, Wout_h, Wout_l, b_out,
            out + (size_t)s * B_ * O_, nullptr, O_);
    }
    (void)in_sizes; (void)n_in;
}

// Round 6
// 14301.691 us; speedup vs baseline: 1.1682x; 1.1682x over previous
//
#include <hip/hip_runtime.h>
#include <hip/hip_bf16.h>
#include <type_traits>

// ---------------------------------------------------------------------------
// Seq2SeqAttention R10: split-K 1024-thread encoder blocks + spread attn_context.
//   R9 post-mortem: VALU cut + tree barrier -> no change; step is memory-
//   service bound: either load latency at 2 waves/SIMD or per-XCD L2 BW.
//   R10a: encoder blocks go 512->1024 threads; waves 0-7 do K[0,512),
//   waves 8-15 K[512,1024) (x K-halves likewise); two Gt halves summed at
//   cell update. Doubles waves/SIMD (latency hiding), halves per-wave
//   critical chain. L2 volume unchanged -> discriminating experiment.
//   R10b: attn_context was 128 blocks (half the CUs) streaming 134MB/step;
//   now 256 blocks x t-halves -> fp32 partials (1MB) + combine kernel.
// MFMA 16x16x32 bf16 layouts (m89/m91-verified): A[m=lane&15][k=quad*8+j],
// B[k=quad*8+j][n=lane&15], D col=lane&15 row=quad*4+reg.
// ---------------------------------------------------------------------------

static constexpr int T_ = 512, B_ = 128, I_ = 256, H_ = 1024, O_ = 256;

typedef unsigned short ushort;
typedef unsigned long long u64;
typedef __attribute__((ext_vector_type(8))) short bf16x8;
typedef __attribute__((ext_vector_type(4))) float f32x4;
typedef __attribute__((ext_vector_type(4))) unsigned uint4_t;
typedef __attribute__((ext_vector_type(8))) _Float16 half8;

__device__ __forceinline__ float bf2f(ushort u) {
    union { unsigned i; float f; } cv; cv.i = ((unsigned)u) << 16; return cv.f;
}
__device__ __forceinline__ ushort f2bf(float f) {   // RNE
    union { float f; unsigned u; } c; c.f = f;
    unsigned r = c.u + 0x7FFFu + ((c.u >> 16) & 1u);
    return (ushort)(r >> 16);
}
__device__ __forceinline__ float fast_sigmoid(float x) { return 1.f / (1.f + __expf(-x)); }
__device__ __forceinline__ float fast_tanh(float x) {
    float ax = fabsf(x);
    float e = __expf(-2.f * ax);
    float t = (1.f - e) / (1.f + e);
    return copysignf(t, x);
}
__device__ __forceinline__ f32x4 mfma16(bf16x8 a, bf16x8 b, f32x4 c) {
    return __builtin_amdgcn_mfma_f32_16x16x32_bf16(a, b, c, 0, 0, 0);
}
__device__ __forceinline__ bf16x8 ld8(const ushort* p) { return *(const bf16x8*)(const void*)p; }

// ---- panel-layout fragment loads -------------------------------------------
// h-like buffer [B_=128][H] as [t][chunk=h>>2][b][4]; row = t*128+b.
__device__ __forceinline__ bf16x8 ld8p(const ushort* base, int row, int ko) {
    const size_t t = (size_t)(row >> 7);
    const int b = row & 127;
    const ushort* p0 = base + t * (size_t)(B_ * H_) + ((size_t)((ko >> 2) * B_ + b) << 2);
    union { u64 q[2]; bf16x8 v; } u;
    u.q[0] = *(const u64*)(const void*)p0;
    u.q[1] = *(const u64*)(const void*)(p0 + (B_ << 2));
    return u.v;
}

// ---- split 8 fp32 into bf16 hi/lo fragments --------------------------------
__device__ __forceinline__ void split8(const float* p, bf16x8& hi, bf16x8& lo) {
    #pragma unroll
    for (int j = 0; j < 8; j++) {
        const float f = p[j];
        const ushort h = f2bf(f);
        hi[j] = (short)h;
        lo[j] = (short)f2bf(f - bf2f(h));
    }
}

// ---- weight split pre-pass -------------------------------------------------
__global__ __launch_bounds__(256) void split_w(
    const float* __restrict__ src, int srcld, int coloff,
    ushort* __restrict__ hi, ushort* __restrict__ lo, int K)
{
    const int k = blockIdx.x * 256 + threadIdx.x;
    const int r = blockIdx.y;
    const float f = src[(size_t)r * srcld + coloff + k];
    const ushort h = f2bf(f);
    hi[(size_t)r * K + k] = h;
    lo[(size_t)r * K + k] = f2bf(f - bf2f(h));
}

// ---- in-place x pack: fp32 -> (bf16hi | bf16lo<<16), same addresses --------
__global__ __launch_bounds__(256) void pack_x(float* __restrict__ x)
{
    const size_t i = ((size_t)blockIdx.x * 256 + threadIdx.x) * 8;
    float4 a = *(const float4*)(x + i);
    float4 b = *(const float4*)(x + i + 4);
    unsigned w[8];
    const float f_[8] = {a.x, a.y, a.z, a.w, b.x, b.y, b.z, b.w};
    #pragma unroll
    for (int j = 0; j < 8; j++) {
        const ushort h = f2bf(f_[j]);
        const ushort l = f2bf(f_[j] - bf2f(h));
        w[j] = (unsigned)h | ((unsigned)l << 16);
    }
    *(uint4_t*)(void*)(x + i)     = uint4_t{w[0], w[1], w[2], w[3]};
    *(uint4_t*)(void*)(x + i + 4) = uint4_t{w[4], w[5], w[6], w[7]};
}

// ---------------------------------------------------------------------------
// Persistent encoder: 256 blocks (1/CU), 1024 threads (16 waves, 4/SIMD).
// Block owns 4 h-values (16 gate-cols) x all 128 batch rows.
// Wave w: row-tile rt=w&7 (16 batch rows), K-half kw=w>>3.
//   seg1 (h@Whh): kc in [kw*512, kw*512+512); seg2 (x): [kw*128, +128).
// LDS: Whh hi/lo [32][64][8] + Wih hi/lo [8][64][8] + Gt[2][16][132].
// hi: ctx_seq history (plain virgin loads). lo: 256-slot virgin ring.
// Barrier: 2-level tree (16 leaves + root), fence-free, monotonic.
// ---------------------------------------------------------------------------
#define ENC_SMEM_BYTES (32*64*8*2*2 + 8*64*8*2*2 + 2*16*132*4)   // 98816
#define LORING_SLOTS 256
// barbuf layout (u32 idx): [0]=release, [32]=root, [64+g*16]=leaf g (g<16)

__global__ __launch_bounds__(1024) void enc_persistent(
    const unsigned* __restrict__ xpk,             // packed x [t][b][k] u32
    const ushort* __restrict__ WhhE_h, const ushort* __restrict__ WhhE_l,
    const ushort* __restrict__ WihE_h, const ushort* __restrict__ WihE_l,
    const float* __restrict__ bih, const float* __restrict__ bhh,
    const ushort* __restrict__ hzero,
    ushort* __restrict__ ctx_seq,                 // panel [t][c][b][4], hi history
    ushort* __restrict__ loring,                  // panel ring [256][c][b][4]
    ushort* __restrict__ enc_lo_fin,              // final lo (survives P-GEMM)
    unsigned* __restrict__ bar)
{
    extern __shared__ __align__(16) char smem[];
    ushort* LWh = (ushort*)smem;                 // Whh hi  [32][64][8]
    ushort* LWl = LWh + 32 * 64 * 8;             // Whh lo
    ushort* LIh = LWl + 32 * 64 * 8;             // Wih hi  [8][64][8]
    ushort* LIl = LIh + 8 * 64 * 8;              // Wih lo
    float*  Gt  = (float*)(LIl + 8 * 64 * 8);    // [2][16 cols][132]

    const int tid  = threadIdx.x;
    const int wave = tid >> 6, lane = tid & 63;
    const int quad = lane >> 4, l15 = lane & 15;
    const int rt   = wave & 7;        // row-tile (16 batch rows)
    const int kw   = wave >> 3;       // K-half
    const int bx   = blockIdx.x;
    const int h0   = bx << 2;
    const int wr   = ((l15 >> 2) * H_) + h0 + (l15 & 3);   // gate*H + h row of W

    // ---- stage weights into LDS (lane-major fragments; done once) ----
    {
        const size_t woff = (size_t)wr * H_;
        #pragma unroll
        for (int ii = 0; ii < 2; ii++) {
            const int i   = (ii << 4) + wave;          // K-iter index 0..31
            const int src = (i << 5) + (quad << 3);
            *(bf16x8*)(LWh + ((i << 6) + lane) * 8) = ld8(WhhE_h + woff + src);
            *(bf16x8*)(LWl + ((i << 6) + lane) * 8) = ld8(WhhE_l + woff + src);
        }
        if (wave < 8) {
            const size_t ioff = (size_t)wr * I_;
            const int src2 = (wave << 5) + (quad << 3);    // K-iter = wave (0..7)
            *(bf16x8*)(LIh + ((wave << 6) + lane) * 8) = ld8(WihE_h + ioff + src2);
            *(bf16x8*)(LIl + ((wave << 6) + lane) * 8) = ld8(WihE_l + ioff + src2);
        }
    }

    // per-thread cell-update mapping (threads < 512) + persistent state
    const int bl_  = tid >> 2, hl = tid & 3;
    const int hidx = h0 + hl;
    const float bs0 = bih[hidx]           + bhh[hidx];
    const float bs1 = bih[H_ + hidx]      + bhh[H_ + hidx];
    const float bs2 = bih[2 * H_ + hidx]  + bhh[2 * H_ + hidx];
    const float bs3 = bih[3 * H_ + hidx]  + bhh[3 * H_ + hidx];
    float c_reg = 0.f;
    __syncthreads();

    const int arow = (rt << 4) + l15;   // batch row for MFMA A (0..127)
    const size_t xoff = (size_t)arow * I_;
    const int kx0 = kw << 7;            // x K-half base (0 or 128)
    const int kh0 = kw << 9;            // h K-half base (0 or 512)

    for (int t = 0; t < T_; t++) {
        const unsigned* xs = xpk + (size_t)t * (B_ * I_) + xoff;

        f32x4 acc0 = {0.f, 0.f, 0.f, 0.f}, acc1 = acc0, acc2 = acc0;
        // ---- seg2 FIRST: x @ Wih^T K-half (h-independent; overlaps barrier)
        #pragma unroll
        for (int kk = 0; kk < 128; kk += 32) {
            const int kc = kx0 + kk;
            const int i = kc >> 5;
            const bf16x8 bh = *(const bf16x8*)(LIh + ((i << 6) + lane) * 8);
            const bf16x8 bl = *(const bf16x8*)(LIl + ((i << 6) + lane) * 8);
            const uint4_t w0 = *(const uint4_t*)(const void*)(xs + kc + (quad << 3));
            const uint4_t w1 = *(const uint4_t*)(const void*)(xs + kc + (quad << 3) + 4);
            bf16x8 ah, al;
            ah[0] = (short)(w0.x & 0xffff); al[0] = (short)(w0.x >> 16);
            ah[1] = (short)(w0.y & 0xffff); al[1] = (short)(w0.y >> 16);
            ah[2] = (short)(w0.z & 0xffff); al[2] = (short)(w0.z >> 16);
            ah[3] = (short)(w0.w & 0xffff); al[3] = (short)(w0.w >> 16);
            ah[4] = (short)(w1.x & 0xffff); al[4] = (short)(w1.x >> 16);
            ah[5] = (short)(w1.y & 0xffff); al[5] = (short)(w1.y >> 16);
            ah[6] = (short)(w1.z & 0xffff); al[6] = (short)(w1.z >> 16);
            ah[7] = (short)(w1.w & 0xffff); al[7] = (short)(w1.w >> 16);
            acc0 = mfma16(ah, bh, acc0);
            acc1 = mfma16(ah, bl, acc1);
            acc2 = mfma16(al, bh, acc2);
        }

        // ---- wait: h_{t-1} published (release of step t) ----
        if (t != 0) {
            if (tid == 0) {
                while (__hip_atomic_load(&bar[0], __ATOMIC_RELAXED,
                                         __HIP_MEMORY_SCOPE_AGENT) < (unsigned)t)
                    __builtin_amdgcn_s_sleep(2);
            }
            __syncthreads();
        }

        // ---- seg1: h @ Whh^T K-half (weights LDS; hi+lo plain virgin loads)
        const ushort* hi_src = t ? (ctx_seq + (size_t)(t - 1) * (B_ * H_)) : hzero;
        const ushort* lo_src = t ? (loring + (size_t)((t - 1) & (LORING_SLOTS - 1))
                                             * (B_ * H_)) : hzero;
        #pragma unroll 8
        for (int kk = 0; kk < 512; kk += 32) {
            const int kc = kh0 + kk;
            const int i  = kc >> 5;
            const int ko = kc + (quad << 3);
            const bf16x8 bh = *(const bf16x8*)(LWh + ((i << 6) + lane) * 8);
            const bf16x8 bl = *(const bf16x8*)(LWl + ((i << 6) + lane) * 8);
            const bf16x8 ah = ld8p(hi_src, arow, ko);
            const bf16x8 al = ld8p(lo_src, arow, ko);
            acc0 = mfma16(ah, bh, acc0);
            acc1 = mfma16(ah, bl, acc1);
            acc2 = mfma16(al, bh, acc2);
        }
        // gate exchange: Gt[kw][col][row]; D: row=quad*4+r, col=l15
        #pragma unroll
        for (int r = 0; r < 4; r++)
            Gt[kw * (16 * 132) + l15 * 132 + (rt << 4) + (quad << 2) + r] =
                acc0[r] + acc1[r] + acc2[r];
        __syncthreads();

        // cell update (threads < 512 -> (batch row bl_, h-local hl)); c in reg
        ushort hh = 0, hlo = 0;
        if (tid < 512) {
            const float gi = Gt[hl * 132 + bl_]        + Gt[16*132 + hl * 132 + bl_]        + bs0;
            const float gf = Gt[(4 + hl) * 132 + bl_]  + Gt[16*132 + (4 + hl) * 132 + bl_]  + bs1;
            const float gg = Gt[(8 + hl) * 132 + bl_]  + Gt[16*132 + (8 + hl) * 132 + bl_]  + bs2;
            const float go = Gt[(12 + hl) * 132 + bl_] + Gt[16*132 + (12 + hl) * 132 + bl_] + bs3;
            const float ig = fast_sigmoid(gi), fg = fast_sigmoid(gf);
            const float gtv = fast_tanh(gg),   og = fast_sigmoid(go);
            c_reg = fg * c_reg + ig * gtv;
            const float hnew = og * fast_tanh(c_reg);
            hh  = f2bf(hnew);
            hlo = f2bf(hnew - bf2f(hh));
        }
        // panel stores: thread-linear packed 4B sc1 write-through (IC truth)
        const unsigned hp = (unsigned)hh  | (__shfl_down((unsigned)hh, 1)  << 16);
        const unsigned lp = (unsigned)hlo | (__shfl_down((unsigned)hlo, 1) << 16);
        if (tid < 512 && !(tid & 1)) {
            const unsigned pi = ((unsigned)bx << 9) + (unsigned)tid;
            __hip_atomic_store((unsigned*)(void*)&ctx_seq[(size_t)t * (B_ * H_) + pi],
                               hp, __ATOMIC_RELAXED, __HIP_MEMORY_SCOPE_AGENT);
            __hip_atomic_store((unsigned*)(void*)
                               &loring[(size_t)(t & (LORING_SLOTS - 1)) * (B_ * H_) + pi],
                               lp, __ATOMIC_RELAXED, __HIP_MEMORY_SCOPE_AGENT);
            if (t == T_ - 1)   // survives P-GEMM overwriting loring
                *(unsigned*)(void*)&enc_lo_fin[pi] = lp;
        }

        // ---- tree arrival: leaf (bx&15) -> root -> release ----
        if (t != T_ - 1) {
            __syncthreads();   // drains vmcnt: stores IC-visible before arrival
            if (tid == 0) {
                const unsigned tgt = (unsigned)(t + 1) * 16u;
                unsigned* leaf = bar + 64 + ((bx & 15) << 4);   // 64B-spaced
                const unsigned la = __hip_atomic_fetch_add(leaf, 1u, __ATOMIC_RELAXED,
                                                           __HIP_MEMORY_SCOPE_AGENT) + 1;
                if (la == tgt) {
                    const unsigned ra = __hip_atomic_fetch_add(&bar[32], 1u,
                                            __ATOMIC_RELAXED, __HIP_MEMORY_SCOPE_AGENT) + 1;
                    if (ra == tgt)
                        __hip_atomic_store(&bar[0], (unsigned)(t + 1),
                                           __ATOMIC_RELAXED, __HIP_MEMORY_SCOPE_AGENT);
                }
            }
        }
    }
}

// ---- fused LSTM step (decoder). Block: 64 batch rows x 16 gate-cols. -------
// grid (H/4 = 256 colgroups, 2 row-halves). A-side h/x PANEL layout.
template<bool WSPLIT, bool XSPLIT, int KX>
__global__ __launch_bounds__(256) void lstm_mfma(
    const ushort* __restrict__ h_hi, const ushort* __restrict__ h_lo,
    const void* __restrict__ x_p, const ushort* __restrict__ x_lo,
    const void* __restrict__ Whh_a, const void* __restrict__ Whh_b,
    const void* __restrict__ Wih_a, const void* __restrict__ Wih_b,
    const float* __restrict__ bih, const float* __restrict__ bhh,
    const float* __restrict__ c_in, float* __restrict__ c_out,
    ushort* __restrict__ h_out_hi, ushort* __restrict__ h_out_lo)
{
    __shared__ float Gt[16][65];
    const int tid = threadIdx.x;
    const int wave = tid >> 6, lane = tid & 63;
    const int quad = lane >> 4, l15 = lane & 15;
    const int h0 = blockIdx.x << 2;
    const int mbase = (blockIdx.y << 6) + (wave << 4);
    const int arow = mbase + l15;
    const int wr = ((l15 >> 2) * H_) + h0 + (l15 & 3);   // gate*H + h index

    f32x4 acc0 = {0.f,0.f,0.f,0.f}, acc1 = acc0, acc2 = acc0;

    // segment 1: h @ Whh^T, K = 1024, A split (hi+lo), panel A
    {
        const size_t woff = (size_t)wr * H_;
        #pragma unroll 4
        for (int kc = 0; kc < H_; kc += 32) {
            const int ko = kc + quad * 8;
            bf16x8 bh, bl;
            if constexpr (WSPLIT) {
                bh = ld8((const ushort*)Whh_a + woff + ko);
                bl = ld8((const ushort*)Whh_b + woff + ko);
            } else {
                split8((const float*)Whh_a + woff + ko, bh, bl);
            }
            const bf16x8 ah = ld8p(h_hi, arow, ko);
            const bf16x8 al = ld8p(h_lo, arow, ko);
            acc0 = mfma16(ah, bh, acc0);
            acc1 = mfma16(ah, bl, acc1);
            acc2 = mfma16(al, bh, acc2);
        }
    }
    // segment 2: x @ Wih^T, K = KX (x panel when XSPLIT)
    {
        const size_t woff = (size_t)wr * KX;
        #pragma unroll 2
        for (int kc = 0; kc < KX; kc += 32) {
            const int ko = kc + quad * 8;
            bf16x8 bh, bl;
            if constexpr (WSPLIT) {
                bh = ld8((const ushort*)Wih_a + woff + ko);
                bl = ld8((const ushort*)Wih_b + woff + ko);
            } else {
                split8((const float*)Wih_a + woff + ko, bh, bl);
            }
            bf16x8 ah, al;
            if constexpr (XSPLIT) {
                ah = ld8p((const ushort*)x_p, arow, ko);
                al = ld8p(x_lo, arow, ko);
            } else {
                split8((const float*)x_p + (size_t)arow * KX + ko, ah, al);
            }
            acc0 = mfma16(ah, bh, acc0);
            acc1 = mfma16(ah, bl, acc1);
            acc2 = mfma16(al, bh, acc2);
        }
    }
    // gate exchange: Gt[col][local_row]; D: row=quad*4+r, col=l15
    #pragma unroll
    for (int r = 0; r < 4; r++)
        Gt[l15][(wave << 4) + quad * 4 + r] = acc0[r] + acc1[r] + acc2[r];
    __syncthreads();

    // cell update: thread -> (local batch row, h-local)
    const int bl_ = tid >> 2, hl = tid & 3;
    const int b = (blockIdx.y << 6) + bl_;
    const int hidx = h0 + hl;
    const float gi = Gt[hl][bl_]      + bih[hidx]          + bhh[hidx];
    const float gf = Gt[4 + hl][bl_]  + bih[H_ + hidx]     + bhh[H_ + hidx];
    const float gg = Gt[8 + hl][bl_]  + bih[2 * H_ + hidx] + bhh[2 * H_ + hidx];
    const float go = Gt[12 + hl][bl_] + bih[3 * H_ + hidx] + bhh[3 * H_ + hidx];
    const float ig = fast_sigmoid(gi), fg = fast_sigmoid(gf);
    const float gt = fast_tanh(gg),    og = fast_sigmoid(go);
    const float cold = c_in[b * H_ + hidx];
    const float cnew = fg * cold + ig * gt;
    const float hnew = og * fast_tanh(cnew);
    c_out[b * H_ + hidx] = cnew;
    const ushort hh = f2bf(hnew);
    const size_t op = ((size_t)(hidx >> 2) * B_ + b) * 4 + (hidx & 3);   // panel
    h_out_hi[op] = hh;
    h_out_lo[op] = f2bf(hnew - bf2f(hh));
}

// ---- generic MFMA GEMM: C = act(A @ W^T + bias) ----------------------------
// grid (N/(16*NT), M/64). Wave = 1 M-tile(16 rows) x NT N-tiles.
// APANEL: A in panel layout. OM: 0=f32 row-major, 3=split bf16 PANEL out,
// 4=fp16 dual-region row-major (idx<HALF -> out0)
template<bool A_LO, int NT, int OM, bool RELU, int K, bool APANEL>
__global__ __launch_bounds__(256) void gemm_mfma(
    const ushort* __restrict__ Ahi, const ushort* __restrict__ Alo, int lda,
    const ushort* __restrict__ Whi, const ushort* __restrict__ Wlo,
    const float* __restrict__ bias,
    void* __restrict__ out0, void* __restrict__ out1, int ldc)
{
    const int tid = threadIdx.x;
    const int wave = tid >> 6, lane = tid & 63;
    const int quad = lane >> 4, l15 = lane & 15;
    const int colbase = (blockIdx.x * NT) << 4;
    const int row = (blockIdx.y << 6) + (wave << 4) + l15;
    const size_t aoff = (size_t)row * lda;

    f32x4 acc0[NT], acc1[NT], acc2[NT];
    #pragma unroll
    for (int nt = 0; nt < NT; nt++) {
        acc0[nt] = {0.f,0.f,0.f,0.f}; acc1[nt] = acc0[nt]; acc2[nt] = acc0[nt];
    }
    size_t woff[NT];
    #pragma unroll
    for (int nt = 0; nt < NT; nt++)
        woff[nt] = (size_t)(colbase + (nt << 4) + l15) * K;

    #pragma unroll 2
    for (int kc = 0; kc < K; kc += 32) {
        const int ko = kc + quad * 8;
        const bf16x8 ah = APANEL ? ld8p(Ahi, row, ko) : ld8(Ahi + aoff + ko);
        bf16x8 al;
        if (A_LO) al = APANEL ? ld8p(Alo, row, ko) : ld8(Alo + aoff + ko);
        #pragma unroll
        for (int nt = 0; nt < NT; nt++) {
            const bf16x8 bh = ld8(Whi + woff[nt] + ko);
            const bf16x8 bl = ld8(Wlo + woff[nt] + ko);
            acc0[nt] = mfma16(ah, bh, acc0[nt]);
            acc1[nt] = mfma16(ah, bl, acc1[nt]);
            if (A_LO) acc2[nt] = mfma16(al, bh, acc2[nt]);
        }
    }
    const size_t orow0 = ((size_t)blockIdx.y << 6) + (wave << 4) + quad * 4;
    const size_t HALF_IDX = (size_t)32768 * 1024;   // P region boundary
    #pragma unroll
    for (int nt = 0; nt < NT; nt++) {
        const int col = colbase + (nt << 4) + l15;
        const float bv = bias ? bias[col] : 0.f;
        #pragma unroll
        for (int r = 0; r < 4; r++) {
            float v = acc0[nt][r] + acc1[nt][r] + (A_LO ? acc2[nt][r] : 0.f) + bv;
            if (RELU) v = fmaxf(v, 0.f);
            const size_t idx = (orow0 + r) * (size_t)ldc + col;
            if constexpr (OM == 0) {
                ((float*)out0)[idx] = v;
            } else if constexpr (OM == 3) {     // panel bf16 hi/lo
                const size_t idxp = ((size_t)(col >> 2) * B_ + (orow0 + r)) * 4 + (col & 3);
                const ushort h = f2bf(v);
                ((ushort*)out0)[idxp] = h;
                ((ushort*)out1)[idxp] = f2bf(v - bf2f(h));
            } else {   // OM == 4: fp16 dual region, row-major
                if (idx < HALF_IDX) ((_Float16*)out0)[idx] = (_Float16)v;
                else                ((_Float16*)out1)[idx - HALF_IDX] = (_Float16)v;
            }
        }
    }
}

// ---- scores[b][t] = sum_h v[h]*tanh(q[b][h] + P[t][b][h]); P fp16 2-region -
__global__ __launch_bounds__(256) void attn_score_kernel(
    const float* __restrict__ q,
    const _Float16* __restrict__ P0, const _Float16* __restrict__ P1,
    const float* __restrict__ v, float* __restrict__ scores)
{
    const int wave = threadIdx.x >> 6, lane = threadIdx.x & 63;
    const int p = (blockIdx.x << 2) + wave;
    const int t = p >> 7, b = p & 127;
    const size_t base = (size_t)(t * B_ + b) * H_ + (lane << 4);
    const size_t HALF_IDX = (size_t)32768 * 1024;
    const _Float16* pp = (base < HALF_IDX) ? (P0 + base) : (P1 + (base - HALF_IDX));

    const half8 u0 = *(const half8*)(const void*)pp;
    const half8 u1 = *(const half8*)(const void*)(pp + 8);
    float pv[16];
    #pragma unroll
    for (int j = 0; j < 8; j++) { pv[j] = (float)u0[j]; pv[8 + j] = (float)u1[j]; }

    const float* qp = q + b * H_ + (lane << 4);
    const float* vp = v + (lane << 4);
    float sum = 0.f;
    #pragma unroll
    for (int j0 = 0; j0 < 16; j0 += 4) {
        const float4 qv = *(const float4*)(qp + j0);
        const float4 vv = *(const float4*)(vp + j0);
        sum += vv.x * fast_tanh(qv.x + pv[j0 + 0]);
        sum += vv.y * fast_tanh(qv.y + pv[j0 + 1]);
        sum += vv.z * fast_tanh(qv.z + pv[j0 + 2]);
        sum += vv.w * fast_tanh(qv.w + pv[j0 + 3]);
    }
    #pragma unroll
    for (int off = 32; off; off >>= 1) sum += __shfl_down(sum, off);
    if (lane == 0) scores[b * T_ + t] = sum;
}

// ---- softmax over t; reads scores[b][t], writes transposed scT[t][b] -------
__global__ __launch_bounds__(256) void softmax_kernel(
    const float* __restrict__ scores, float* __restrict__ scT)
{
    __shared__ float red[256];
    const int b = blockIdx.x, tid = threadIdx.x;
    const float s0 = scores[b * T_ + tid];
    const float s1 = scores[b * T_ + tid + 256];
    red[tid] = fmaxf(s0, s1);
    __syncthreads();
    for (int off = 128; off; off >>= 1) {
        if (tid < off) red[tid] = fmaxf(red[tid], red[tid + off]);
        __syncthreads();
    }
    const float mx = red[0];
    __syncthreads();
    const float e0 = __expf(s0 - mx), e1 = __expf(s1 - mx);
    red[tid] = e0 + e1;
    __syncthreads();
    for (int off = 128; off; off >>= 1) {
        if (tid < off) red[tid] += red[tid + off];
        __syncthreads();
    }
    const float inv = 1.f / red[0];
    scT[tid * B_ + b] = e0 * inv;
    scT[(tid + 256) * B_ + b] = e1 * inv;
}

// ---- context partial: pctx[(cb*2+half)] = sum_{t in half} scT[t][b]*ctx ----
// grid 256 blocks x 256 thr = 65536; cb = (c,b); spreads BW over all CUs.
__global__ __launch_bounds__(256) void attn_context_part(
    const float* __restrict__ scT, const ushort* __restrict__ ctx,
    float* __restrict__ pctx)
{
    const int u = blockIdx.x * 256 + threadIdx.x;
    const int cb = u & 32767;
    const int half = u >> 15;
    const int c = cb >> 7, b = cb & 127;
    const ushort* cp = ctx + ((size_t)(c * B_ + b) << 2)
                           + (size_t)(half << 8) * (B_ * H_);
    const float* wp = scT + ((half << 8) * B_) + b;
    float a0 = 0.f, a1 = 0.f, a2 = 0.f, a3 = 0.f;
    #pragma unroll 4
    for (int t = 0; t < 256; t++) {
        const float w = wp[t << 7];
        const u64 raw = *(const u64*)(const void*)(cp + (size_t)t * (B_ * H_));
        a0 += w * bf2f((ushort)raw);
        a1 += w * bf2f((ushort)(raw >> 16));
        a2 += w * bf2f((ushort)(raw >> 32));
        a3 += w * bf2f((ushort)(raw >> 48));
    }
    float4 o = {a0, a1, a2, a3};
    *(float4*)(void*)(pctx + ((size_t)(cb << 1) + half) * 4) = o;
}

// ---- context finalize: add halves, split to panel bf16 hi/lo ---------------
__global__ __launch_bounds__(256) void attn_context_fin(
    const float* __restrict__ pctx,
    ushort* __restrict__ chi, ushort* __restrict__ clo)
{
    const int cb = blockIdx.x * 256 + threadIdx.x;   // 32768
    const float4 x0 = *(const float4*)(pctx + (size_t)cb * 8);
    const float4 x1 = *(const float4*)(pctx + (size_t)cb * 8 + 4);
    const float a0 = x0.x + x1.x, a1 = x0.y + x1.y;
    const float a2 = x0.z + x1.z, a3 = x0.w + x1.w;
    const size_t i0 = (size_t)cb << 2;
    const ushort h0 = f2bf(a0), h1 = f2bf(a1), h2 = f2bf(a2), h3 = f2bf(a3);
    const ushort l0 = f2bf(a0 - bf2f(h0)), l1 = f2bf(a1 - bf2f(h1));
    const ushort l2 = f2bf(a2 - bf2f(h2)), l3 = f2bf(a3 - bf2f(h3));
    *(u64*)(void*)&chi[i0] = (u64)h0 | ((u64)h1 << 16) | ((u64)h2 << 32) | ((u64)h3 << 48);
    *(u64*)(void*)&clo[i0] = (u64)l0 | ((u64)l1 << 16) | ((u64)l2 << 32) | ((u64)l3 << 48);
}

// ---------------------------------------------------------------------------
extern "C" void kernel_launch(void* const* d_in, const int* in_sizes, int n_in,
                              void* d_out, int out_size, void* d_ws, size_t ws_size,
                              hipStream_t stream)
{
    const float* input_seq = (const float*)d_in[0];
    const float* W_ih_enc  = (const float*)d_in[1];
    const float* W_hh_enc  = (const float*)d_in[2];
    const float* b_ih_enc  = (const float*)d_in[3];
    const float* b_hh_enc  = (const float*)d_in[4];
    const float* W_attn    = (const float*)d_in[5];
    const float* b_attn    = (const float*)d_in[6];
    const float* v         = (const float*)d_in[7];
    const float* W_ih_dec  = (const float*)d_in[8];
    const float* W_hh_dec  = (const float*)d_in[9];
    const float* b_ih_dec  = (const float*)d_in[10];
    const float* b_hh_dec  = (const float*)d_in[11];
    const float* W_dec     = (const float*)d_in[12];
    const float* b_dec     = (const float*)d_in[13];
    const float* W_out     = (const float*)d_in[14];
    const float* b_out     = (const float*)d_in[15];
    float* out = (float*)d_out;
    const int LEN = out_size / (B_ * O_);   // 30
    const int BH = B_ * H_;

    char* ws = (char*)d_ws;
    size_t off = 0;
    auto aus = [&](size_t n) { ushort* p = (ushort*)(ws + off); off += n * 2; return p; };
    auto af  = [&](size_t n) { float*  p = (float*) (ws + off); off += n * 4; return p; };

    // pre-split weights (hot / MFMA-consumed). Decoder LSTM W split on the fly.
    ushort* WhhE_h = aus((size_t)4*H_*H_); ushort* WhhE_l = aus((size_t)4*H_*H_);
    ushort* WihE_h = aus((size_t)4*H_*I_); ushort* WihE_l = aus((size_t)4*H_*I_);
    ushort* Wh_h   = aus((size_t)H_*H_);   ushort* Wh_l   = aus((size_t)H_*H_);
    ushort* Wc_h   = aus((size_t)H_*H_);   ushort* Wc_l   = aus((size_t)H_*H_);
    ushort* Wdec_h = aus((size_t)H_*H_);   ushort* Wdec_l = aus((size_t)H_*H_);
    ushort* Wout_h = aus((size_t)O_*H_);   ushort* Wout_l = aus((size_t)O_*H_);

    ushort* ctx_seq = aus((size_t)T_ * BH);          // hi history, panel layout
    ushort* hzero   = aus(BH);
    ushort* enc_lo_fin = aus(BH);                    // final lo (post-P-GEMM use)
    ushort* hd_hi0  = aus(BH); ushort* hd_hi1  = aus(BH);
    ushort* hd_lo0  = aus(BH); ushort* hd_lo1  = aus(BH);
    ushort* ctx_hi  = aus(BH); ushort* ctx_lo  = aus(BH);
    ushort* d1_hi   = aus(BH); ushort* d1_lo   = aus(BH);
    float*  cbuf    = af(BH);
    float*  qbuf    = af(BH);
    float*  scores  = af(B_ * T_);
    float*  scT     = af(B_ * T_);
    float*  pctx    = af((size_t)32768 * 8);         // context partials (1 MB)
    unsigned* barbuf = (unsigned*)(ws + off); off += 4096;   // tree-barrier state

    // lo ring: 256 slots x 256KB = 67.1 MB. Dead after encoder -> P1 aliases it.
    ushort* loring = aus((size_t)LORING_SLOTS * BH);
    const size_t P_HALF = (size_t)(T_ / 2) * BH * 2;   // 67,108,864 == loring size
    _Float16* P1 = (_Float16*)loring;
    _Float16* P0;
    if (ws_size >= off + P_HALF) {            // spare ws for P0
        P0 = (_Float16*)(ws + off);
    } else {                                   // alias input_seq (dead after enc)
        P0 = (_Float16*)const_cast<float*>(input_seq);
    }

    // ---- weight split pre-pass ----
    auto spl = [&](const float* src, int srcld, int coloff, ushort* hi, ushort* lo,
                   int R, int K) {
        split_w<<<dim3(K / 256, R), 256, 0, stream>>>(src, srcld, coloff, hi, lo, K);
    };
    spl(W_hh_enc, H_,     0,  WhhE_h, WhhE_l, 4 * H_, H_);
    spl(W_ih_enc, I_,     0,  WihE_h, WihE_l, 4 * H_, I_);
    spl(W_attn,   2 * H_, 0,  Wh_h,   Wh_l,   H_,     H_);
    spl(W_attn,   2 * H_, H_, Wc_h,   Wc_l,   H_,     H_);
    spl(W_dec,    H_,     0,  Wdec_h, Wdec_l, H_,     H_);
    spl(W_out,    H_,     0,  Wout_h, Wout_l, O_,     H_);

    // ---- in-place pack of x: fp32 -> (bf16hi | bf16lo<<16) ----
    pack_x<<<(T_ * B_ * I_) / (256 * 8), 256, 0, stream>>>(
        const_cast<float*>(input_seq));

    hipMemsetAsync(hzero,  0, (size_t)BH * 2, stream);   // h_{-1} = lo_{-1} = 0
    hipMemsetAsync(barbuf, 0, 4096, stream);

    // ---- encoder: ONE persistent kernel, 512 steps, split-K 16 waves ----
    enc_persistent<<<dim3(H_ / 4), 1024, ENC_SMEM_BYTES, stream>>>(
        (const unsigned*)input_seq, WhhE_h, WhhE_l, WihE_h, WihE_l,
        b_ih_enc, b_hh_enc, hzero, ctx_seq, loring, enc_lo_fin, barbuf);
    // enc final: hi = ctx_seq[511] (panel), lo = enc_lo_fin (panel)

    // ---- P = ctx_seq @ W_c^T + b_attn  (fp16 row-major, dual region;
    //      P1 overwrites loring, P0 may overwrite input_seq — both dead) ----
    gemm_mfma<false, 8, 4, false, H_, true><<<dim3(8, (T_ * B_) / 64), 256, 0, stream>>>(
        ctx_seq, nullptr, H_, Wc_h, Wc_l, b_attn, P0, P1, H_);

    // ---- decoder ----
    hipMemsetAsync(cbuf, 0, (size_t)BH * 4, stream);
    ushort* dhh[2] = {hd_hi0, hd_hi1};
    ushort* dhl[2] = {hd_lo0, hd_lo1};
    for (int s = 0; s < LEN; s++) {
        const ushort* hi_in = (s == 0) ? ctx_seq + (size_t)(T_ - 1) * BH : dhh[s & 1];
        const ushort* lo_in = (s == 0) ? enc_lo_fin : dhl[s & 1];

        // q = h @ W_h^T (bias folded into P)
        gemm_mfma<true, 1, 0, false, H_, true><<<dim3(H_ / 16, 2), 256, 0, stream>>>(
            hi_in, lo_in, H_, Wh_h, Wh_l, nullptr, qbuf, nullptr, H_);
        attn_score_kernel<<<T_ * B_ / 4, 256, 0, stream>>>(qbuf, P0, P1, v, scores);
        softmax_kernel<<<B_, 256, 0, stream>>>(scores, scT);
        attn_context_part<<<256, 256, 0, stream>>>(scT, ctx_seq, pctx);
        attn_context_fin<<<128, 256, 0, stream>>>(pctx, ctx_hi, ctx_lo);
        // decoder LSTM cell (x = context panel; weights split on the fly)
        lstm_mfma<false, true, H_><<<dim3(H_ / 4, 2), 256, 0, stream>>>(
            hi_in, lo_in, (const void*)ctx_hi, ctx_lo,
            W_hh_dec, nullptr, W_ih_dec, nullptr, b_ih_dec, b_hh_dec,
            cbuf, cbuf, dhh[(s + 1) & 1], dhl[(s + 1) & 1]);
        // d1 = relu(h @ W_dec^T + b_dec) -> split (panel out)
        gemm_mfma<true, 1, 3, true, H_, true><<<dim3(H_ / 16, 2), 256, 0, stream>>>(
            dhh[(s + 1) & 1], dhl[(s + 1) & 1], H_, Wdec_h, Wdec_l, b_dec,
            d1_hi, d1_lo, H_);
        // out = d1 @ W_out^T + b_out  (fp32 row-major final output)
        gemm_mfma<true, 1, 0, false, H_, true><<<dim3(O_ / 16, 2), 256, 0, stream>>>(
            d1_hi, d1_lo, H_, Wout_h, Wout_l, b_out,
            out + (size_t)s * B_ * O_, nullptr, O_);
    }
    (void)in_sizes; (void)n_in;
}

// Round 7
// 14258.282 us; speedup vs baseline: 1.1718x; 1.0030x over previous
//
#include <hip/hip_runtime.h>
#include <hip/hip_bf16.h>
#include <type_traits>

// ---------------------------------------------------------------------------
// Seq2SeqAttention R11: encoder 64r x 32c retile + packed decoder weights.
//   R10 post-mortem: split-K helped (~12.3us/step) but the floor matches the
//   per-XCD L2 model: every block owned all 128 batch rows -> 20.5MB/XCD/step.
//   R11a: block = 64 rows x 32 gate-cols (grid 256 = 1/CU unchanged);
//   per-XCD h/x traffic halves to ~10.5MB/step. 16 waves = 4 rt x 2 ct x
//   2 kw. Whh hi+lo (32 cols) in 128KB LDS; Wih fragments hoisted to
//   registers ONCE (constant across t). Bit-identical summation order.
//   R11b: decoder LSTM weights packed in place fp32 -> (bf16hi|lo<<16) u32
//   (pack_x trick; harness restores d_in each launch, proven R8-R10).
//   lstm_mfma WPACK mode: cheap and/shift unpack replaces 48-op split8.
// MFMA 16x16x32 bf16 layouts (m89/m91-verified): A[m=lane&15][k=quad*8+j],
// B[k=quad*8+j][n=lane&15], D col=lane&15 row=quad*4+reg.
// ---------------------------------------------------------------------------

static constexpr int T_ = 512, B_ = 128, I_ = 256, H_ = 1024, O_ = 256;

typedef unsigned short ushort;
typedef unsigned long long u64;
typedef __attribute__((ext_vector_type(8))) short bf16x8;
typedef __attribute__((ext_vector_type(4))) float f32x4;
typedef __attribute__((ext_vector_type(4))) unsigned uint4_t;
typedef __attribute__((ext_vector_type(8))) _Float16 half8;

__device__ __forceinline__ float bf2f(ushort u) {
    union { unsigned i; float f; } cv; cv.i = ((unsigned)u) << 16; return cv.f;
}
__device__ __forceinline__ ushort f2bf(float f) {   // RNE
    union { float f; unsigned u; } c; c.f = f;
    unsigned r = c.u + 0x7FFFu + ((c.u >> 16) & 1u);
    return (ushort)(r >> 16);
}
__device__ __forceinline__ float fast_sigmoid(float x) { return 1.f / (1.f + __expf(-x)); }
__device__ __forceinline__ float fast_tanh(float x) {
    float ax = fabsf(x);
    float e = __expf(-2.f * ax);
    float t = (1.f - e) / (1.f + e);
    return copysignf(t, x);
}
__device__ __forceinline__ f32x4 mfma16(bf16x8 a, bf16x8 b, f32x4 c) {
    return __builtin_amdgcn_mfma_f32_16x16x32_bf16(a, b, c, 0, 0, 0);
}
__device__ __forceinline__ bf16x8 ld8(const ushort* p) { return *(const bf16x8*)(const void*)p; }

// ---- panel-layout fragment loads -------------------------------------------
// h-like buffer [B_=128][H] as [t][chunk=h>>2][b][4]; row = t*128+b.
__device__ __forceinline__ bf16x8 ld8p(const ushort* base, int row, int ko) {
    const size_t t = (size_t)(row >> 7);
    const int b = row & 127;
    const ushort* p0 = base + t * (size_t)(B_ * H_) + ((size_t)((ko >> 2) * B_ + b) << 2);
    union { u64 q[2]; bf16x8 v; } u;
    u.q[0] = *(const u64*)(const void*)p0;
    u.q[1] = *(const u64*)(const void*)(p0 + (B_ << 2));
    return u.v;
}

// ---- split 8 fp32 into bf16 hi/lo fragments --------------------------------
__device__ __forceinline__ void split8(const float* p, bf16x8& hi, bf16x8& lo) {
    #pragma unroll
    for (int j = 0; j < 8; j++) {
        const float f = p[j];
        const ushort h = f2bf(f);
        hi[j] = (short)h;
        lo[j] = (short)f2bf(f - bf2f(h));
    }
}

// ---- unpack 8 packed u32 (bf16hi | bf16lo<<16) -> hi/lo fragments ----------
__device__ __forceinline__ void unpack8(const unsigned* p, bf16x8& hi, bf16x8& lo) {
    const uint4_t w0 = *(const uint4_t*)(const void*)p;
    const uint4_t w1 = *(const uint4_t*)(const void*)(p + 4);
    hi[0] = (short)(w0.x & 0xffff); lo[0] = (short)(w0.x >> 16);
    hi[1] = (short)(w0.y & 0xffff); lo[1] = (short)(w0.y >> 16);
    hi[2] = (short)(w0.z & 0xffff); lo[2] = (short)(w0.z >> 16);
    hi[3] = (short)(w0.w & 0xffff); lo[3] = (short)(w0.w >> 16);
    hi[4] = (short)(w1.x & 0xffff); lo[4] = (short)(w1.x >> 16);
    hi[5] = (short)(w1.y & 0xffff); lo[5] = (short)(w1.y >> 16);
    hi[6] = (short)(w1.z & 0xffff); lo[6] = (short)(w1.z >> 16);
    hi[7] = (short)(w1.w & 0xffff); lo[7] = (short)(w1.w >> 16);
}

// ---- weight split pre-pass -------------------------------------------------
__global__ __launch_bounds__(256) void split_w(
    const float* __restrict__ src, int srcld, int coloff,
    ushort* __restrict__ hi, ushort* __restrict__ lo, int K)
{
    const int k = blockIdx.x * 256 + threadIdx.x;
    const int r = blockIdx.y;
    const float f = src[(size_t)r * srcld + coloff + k];
    const ushort h = f2bf(f);
    hi[(size_t)r * K + k] = h;
    lo[(size_t)r * K + k] = f2bf(f - bf2f(h));
}

// ---- in-place pack: fp32 -> (bf16hi | bf16lo<<16), same addresses ----------
__global__ __launch_bounds__(256) void pack_x(float* __restrict__ x)
{
    const size_t i = ((size_t)blockIdx.x * 256 + threadIdx.x) * 8;
    float4 a = *(const float4*)(x + i);
    float4 b = *(const float4*)(x + i + 4);
    unsigned w[8];
    const float f_[8] = {a.x, a.y, a.z, a.w, b.x, b.y, b.z, b.w};
    #pragma unroll
    for (int j = 0; j < 8; j++) {
        const ushort h = f2bf(f_[j]);
        const ushort l = f2bf(f_[j] - bf2f(h));
        w[j] = (unsigned)h | ((unsigned)l << 16);
    }
    *(uint4_t*)(void*)(x + i)     = uint4_t{w[0], w[1], w[2], w[3]};
    *(uint4_t*)(void*)(x + i + 4) = uint4_t{w[4], w[5], w[6], w[7]};
}

// ---------------------------------------------------------------------------
// Persistent encoder: 256 blocks (1/CU), 1024 threads (16 waves, 4/SIMD).
// Block bx: colgroup cg=bx>>1 (h-cols [cg*8,+8) = 32 gate-cols), rowhalf
// rh=bx&1 (batch rows [rh*64,+64)). Wave = rt(4 row-tiles) x ct(2 col-tiles)
// x kw(2 K-halves). Per-block A-side reads HALVED vs R10 (64 rows).
// LDS: Whh hi/lo [2ct][32i][64lane][8] (128KB) + Gt [2kw][32bc][68] (17KB).
// Wih fragments hoisted to registers once (constant over t).
// hi: ctx_seq history (plain virgin loads). lo: 256-slot virgin ring.
// Barrier: 2-level tree (16 leaves + root), fence-free, monotonic.
// ---------------------------------------------------------------------------
#define ENC_SMEM_BYTES (2*32*64*8*2*2 + 2*32*68*4)   // 131072 + 17408 = 148480
#define LORING_SLOTS 256
// barbuf layout (u32 idx): [0]=release, [32]=root, [64+g*16]=leaf g (g<16)

__global__ __launch_bounds__(1024) void enc_persistent(
    const unsigned* __restrict__ xpk,             // packed x [t][b][k] u32
    const ushort* __restrict__ WhhE_h, const ushort* __restrict__ WhhE_l,
    const ushort* __restrict__ WihE_h, const ushort* __restrict__ WihE_l,
    const float* __restrict__ bih, const float* __restrict__ bhh,
    const ushort* __restrict__ hzero,
    ushort* __restrict__ ctx_seq,                 // panel [t][c][b][4], hi history
    ushort* __restrict__ loring,                  // panel ring [256][c][b][4]
    ushort* __restrict__ enc_lo_fin,              // final lo (survives P-GEMM)
    unsigned* __restrict__ bar)
{
    extern __shared__ __align__(16) char smem[];
    ushort* LWh = (ushort*)smem;                   // Whh hi [2ct][32i][64][8]
    ushort* LWl = LWh + 2 * 32 * 64 * 8;           // Whh lo
    float*  Gt  = (float*)(LWl + 2 * 32 * 64 * 8); // [2kw][32bc][68]

    const int tid  = threadIdx.x;
    const int wave = tid >> 6, lane = tid & 63;
    const int quad = lane >> 4, l15 = lane & 15;
    const int rt = wave & 3, ct = (wave >> 2) & 1, kw = wave >> 3;
    const int bx = blockIdx.x;
    const int cg = bx >> 1;                  // h-cols [cg*8, cg*8+8)
    const int rh = bx & 1;                   // batch rows [rh*64, +64)
    const int wr = (l15 >> 2) * H_ + (cg << 3) + (ct << 2) + (l15 & 3);

    // ---- stage Whh hi/lo into LDS (64 (ct,i) frag-sets, 4 per wave) ----
    #pragma unroll
    for (int ii = 0; ii < 4; ii++) {
        const int pair = (wave << 2) + ii;
        const int cts = pair >> 5, is = pair & 31;
        const int wrs = (l15 >> 2) * H_ + (cg << 3) + (cts << 2) + (l15 & 3);
        const int fo  = ((((cts << 5) | is) << 6) | lane) << 3;
        const int src = (is << 5) + (quad << 3);
        *(bf16x8*)(LWh + fo) = ld8(WhhE_h + (size_t)wrs * H_ + src);
        *(bf16x8*)(LWl + fo) = ld8(WhhE_l + (size_t)wrs * H_ + src);
    }
    // ---- hoist Wih fragments to registers (constant across t) ----
    bf16x8 wih_h[4], wih_l[4];
    #pragma unroll
    for (int kk = 0; kk < 4; kk++) {
        const int ko = (kw << 7) + (kk << 5) + (quad << 3);
        wih_h[kk] = ld8(WihE_h + (size_t)wr * I_ + ko);
        wih_l[kk] = ld8(WihE_l + (size_t)wr * I_ + ko);
    }

    // per-thread cell-update mapping (threads < 512) + persistent state
    const int c2   = (tid >> 8) & 1, lrow = (tid >> 2) & 63, h2 = tid & 3;
    const int hidx = (cg << 3) + (c2 << 2) + h2;
    const float bs0 = bih[hidx]           + bhh[hidx];
    const float bs1 = bih[H_ + hidx]      + bhh[H_ + hidx];
    const float bs2 = bih[2 * H_ + hidx]  + bhh[2 * H_ + hidx];
    const float bs3 = bih[3 * H_ + hidx]  + bhh[3 * H_ + hidx];
    float c_reg = 0.f;
    __syncthreads();

    const int arow = (rh << 6) + (rt << 4) + l15;   // batch row (0..127)
    const size_t xoff = (size_t)arow * I_;

    for (int t = 0; t < T_; t++) {
        const unsigned* xs = xpk + (size_t)t * (B_ * I_) + xoff;

        f32x4 acc0 = {0.f, 0.f, 0.f, 0.f}, acc1 = acc0, acc2 = acc0;
        // ---- seg2 FIRST: x @ Wih^T K-half (h-independent; overlaps barrier)
        #pragma unroll
        for (int kk = 0; kk < 4; kk++) {
            const int ko = (kw << 7) + (kk << 5) + (quad << 3);
            bf16x8 ah, al;
            unpack8(xs + ko, ah, al);
            acc0 = mfma16(ah, wih_h[kk], acc0);
            acc1 = mfma16(ah, wih_l[kk], acc1);
            acc2 = mfma16(al, wih_h[kk], acc2);
        }

        // ---- wait: h_{t-1} published (release of step t) ----
        if (t != 0) {
            if (tid == 0) {
                while (__hip_atomic_load(&bar[0], __ATOMIC_RELAXED,
                                         __HIP_MEMORY_SCOPE_AGENT) < (unsigned)t)
                    __builtin_amdgcn_s_sleep(2);
            }
            __syncthreads();
        }

        // ---- seg1: h @ Whh^T K-half (weights LDS; hi+lo plain virgin loads)
        const ushort* hi_src = t ? (ctx_seq + (size_t)(t - 1) * (B_ * H_)) : hzero;
        const ushort* lo_src = t ? (loring + (size_t)((t - 1) & (LORING_SLOTS - 1))
                                             * (B_ * H_)) : hzero;
        #pragma unroll 8
        for (int kk = 0; kk < 512; kk += 32) {
            const int i  = (kw << 4) + (kk >> 5);
            const int fo = ((((ct << 5) | i) << 6) | lane) << 3;
            const int ko = (kw << 9) + kk + (quad << 3);
            const bf16x8 bh = *(const bf16x8*)(LWh + fo);
            const bf16x8 bl = *(const bf16x8*)(LWl + fo);
            const bf16x8 ah = ld8p(hi_src, arow, ko);
            const bf16x8 al = ld8p(lo_src, arow, ko);
            acc0 = mfma16(ah, bh, acc0);
            acc1 = mfma16(ah, bl, acc1);
            acc2 = mfma16(al, bh, acc2);
        }
        // gate exchange: Gt[kw][bc][row]; D: row=quad*4+r, col=l15
        #pragma unroll
        for (int r = 0; r < 4; r++)
            Gt[kw * 2176 + ((ct << 4) | l15) * 68 + (rt << 4) + (quad << 2) + r] =
                acc0[r] + acc1[r] + acc2[r];
        __syncthreads();

        // cell update (threads < 512 -> (lrow, c2*4+h2)); c in register
        ushort hh = 0, hlo = 0;
        if (tid < 512) {
            const int bc0 = (c2 << 4) + h2;
            const float gi = Gt[(bc0)      * 68 + lrow] + Gt[2176 + (bc0)      * 68 + lrow] + bs0;
            const float gf = Gt[(bc0 + 4)  * 68 + lrow] + Gt[2176 + (bc0 + 4)  * 68 + lrow] + bs1;
            const float gg = Gt[(bc0 + 8)  * 68 + lrow] + Gt[2176 + (bc0 + 8)  * 68 + lrow] + bs2;
            const float go = Gt[(bc0 + 12) * 68 + lrow] + Gt[2176 + (bc0 + 12) * 68 + lrow] + bs3;
            const float ig = fast_sigmoid(gi), fg = fast_sigmoid(gf);
            const float gtv = fast_tanh(gg),   og = fast_sigmoid(go);
            c_reg = fg * c_reg + ig * gtv;
            const float hnew = og * fast_tanh(c_reg);
            hh  = f2bf(hnew);
            hlo = f2bf(hnew - bf2f(hh));
        }
        // panel stores: thread-linear packed 4B sc1 write-through (IC truth)
        const unsigned hp = (unsigned)hh  | (__shfl_down((unsigned)hh, 1)  << 16);
        const unsigned lp = (unsigned)hlo | (__shfl_down((unsigned)hlo, 1) << 16);
        if (tid < 512 && !(tid & 1)) {
            const unsigned pi = ((unsigned)cg << 10) + ((unsigned)c2 << 9)
                              + ((unsigned)rh << 8) + (unsigned)(tid & 255);
            __hip_atomic_store((unsigned*)(void*)&ctx_seq[(size_t)t * (B_ * H_) + pi],
                               hp, __ATOMIC_RELAXED, __HIP_MEMORY_SCOPE_AGENT);
            __hip_atomic_store((unsigned*)(void*)
                               &loring[(size_t)(t & (LORING_SLOTS - 1)) * (B_ * H_) + pi],
                               lp, __ATOMIC_RELAXED, __HIP_MEMORY_SCOPE_AGENT);
            if (t == T_ - 1)   // survives P-GEMM overwriting loring
                *(unsigned*)(void*)&enc_lo_fin[pi] = lp;
        }

        // ---- tree arrival: leaf (bx&15) -> root -> release ----
        if (t != T_ - 1) {
            __syncthreads();   // drains vmcnt: stores IC-visible before arrival
            if (tid == 0) {
                const unsigned tgt = (unsigned)(t + 1) * 16u;
                unsigned* leaf = bar + 64 + ((bx & 15) << 4);   // 64B-spaced
                const unsigned la = __hip_atomic_fetch_add(leaf, 1u, __ATOMIC_RELAXED,
                                                           __HIP_MEMORY_SCOPE_AGENT) + 1;
                if (la == tgt) {
                    const unsigned ra = __hip_atomic_fetch_add(&bar[32], 1u,
                                            __ATOMIC_RELAXED, __HIP_MEMORY_SCOPE_AGENT) + 1;
                    if (ra == tgt)
                        __hip_atomic_store(&bar[0], (unsigned)(t + 1),
                                           __ATOMIC_RELAXED, __HIP_MEMORY_SCOPE_AGENT);
                }
            }
        }
    }
}

// ---- fused LSTM step (decoder). Block: 64 batch rows x 16 gate-cols. -------
// grid (H/4 = 256 colgroups, 2 row-halves). A-side h/x PANEL layout.
// WPACK: weights packed u32 (bf16hi|lo<<16) in Whh_a / Wih_a.
template<bool WPACK, bool XSPLIT, int KX>
__global__ __launch_bounds__(256) void lstm_mfma(
    const ushort* __restrict__ h_hi, const ushort* __restrict__ h_lo,
    const void* __restrict__ x_p, const ushort* __restrict__ x_lo,
    const void* __restrict__ Whh_a,
    const void* __restrict__ Wih_a,
    const float* __restrict__ bih, const float* __restrict__ bhh,
    const float* __restrict__ c_in, float* __restrict__ c_out,
    ushort* __restrict__ h_out_hi, ushort* __restrict__ h_out_lo)
{
    __shared__ float Gt[16][65];
    const int tid = threadIdx.x;
    const int wave = tid >> 6, lane = tid & 63;
    const int quad = lane >> 4, l15 = lane & 15;
    const int h0 = blockIdx.x << 2;
    const int mbase = (blockIdx.y << 6) + (wave << 4);
    const int arow = mbase + l15;
    const int wr = ((l15 >> 2) * H_) + h0 + (l15 & 3);   // gate*H + h index

    f32x4 acc0 = {0.f,0.f,0.f,0.f}, acc1 = acc0, acc2 = acc0;

    // segment 1: h @ Whh^T, K = 1024, A split (hi+lo), panel A
    {
        const size_t woff = (size_t)wr * H_;
        #pragma unroll 4
        for (int kc = 0; kc < H_; kc += 32) {
            const int ko = kc + quad * 8;
            bf16x8 bh, bl;
            if constexpr (WPACK) {
                unpack8((const unsigned*)Whh_a + woff + ko, bh, bl);
            } else {
                split8((const float*)Whh_a + woff + ko, bh, bl);
            }
            const bf16x8 ah = ld8p(h_hi, arow, ko);
            const bf16x8 al = ld8p(h_lo, arow, ko);
            acc0 = mfma16(ah, bh, acc0);
            acc1 = mfma16(ah, bl, acc1);
            acc2 = mfma16(al, bh, acc2);
        }
    }
    // segment 2: x @ Wih^T, K = KX (x panel when XSPLIT)
    {
        const size_t woff = (size_t)wr * KX;
        #pragma unroll 2
        for (int kc = 0; kc < KX; kc += 32) {
            const int ko = kc + quad * 8;
            bf16x8 bh, bl;
            if constexpr (WPACK) {
                unpack8((const unsigned*)Wih_a + woff + ko, bh, bl);
            } else {
                split8((const float*)Wih_a + woff + ko, bh, bl);
            }
            bf16x8 ah, al;
            if constexpr (XSPLIT) {
                ah = ld8p((const ushort*)x_p, arow, ko);
                al = ld8p(x_lo, arow, ko);
            } else {
                split8((const float*)x_p + (size_t)arow * KX + ko, ah, al);
            }
            acc0 = mfma16(ah, bh, acc0);
            acc1 = mfma16(ah, bl, acc1);
            acc2 = mfma16(al, bh, acc2);
        }
    }
    // gate exchange: Gt[col][local_row]; D: row=quad*4+r, col=l15
    #pragma unroll
    for (int r = 0; r < 4; r++)
        Gt[l15][(wave << 4) + quad * 4 + r] = acc0[r] + acc1[r] + acc2[r];
    __syncthreads();

    // cell update: thread -> (local batch row, h-local)
    const int bl_ = tid >> 2, hl = tid & 3;
    const int b = (blockIdx.y << 6) + bl_;
    const int hidx = h0 + hl;
    const float gi = Gt[hl][bl_]      + bih[hidx]          + bhh[hidx];
    const float gf = Gt[4 + hl][bl_]  + bih[H_ + hidx]     + bhh[H_ + hidx];
    const float gg = Gt[8 + hl][bl_]  + bih[2 * H_ + hidx] + bhh[2 * H_ + hidx];
    const float go = Gt[12 + hl][bl_] + bih[3 * H_ + hidx] + bhh[3 * H_ + hidx];
    const float ig = fast_sigmoid(gi), fg = fast_sigmoid(gf);
    const float gt = fast_tanh(gg),    og = fast_sigmoid(go);
    const float cold = c_in[b * H_ + hidx];
    const float cnew = fg * cold + ig * gt;
    const float hnew = og * fast_tanh(cnew);
    c_out[b * H_ + hidx] = cnew;
    const ushort hh = f2bf(hnew);
    const size_t op = ((size_t)(hidx >> 2) * B_ + b) * 4 + (hidx & 3);   // panel
    h_out_hi[op] = hh;
    h_out_lo[op] = f2bf(hnew - bf2f(hh));
}

// ---- generic MFMA GEMM: C = act(A @ W^T + bias) ----------------------------
// grid (N/(16*NT), M/64). Wave = 1 M-tile(16 rows) x NT N-tiles.
// APANEL: A in panel layout. OM: 0=f32 row-major, 3=split bf16 PANEL out,
// 4=fp16 dual-region row-major (idx<HALF -> out0)
template<bool A_LO, int NT, int OM, bool RELU, int K, bool APANEL>
__global__ __launch_bounds__(256) void gemm_mfma(
    const ushort* __restrict__ Ahi, const ushort* __restrict__ Alo, int lda,
    const ushort* __restrict__ Whi, const ushort* __restrict__ Wlo,
    const float* __restrict__ bias,
    void* __restrict__ out0, void* __restrict__ out1, int ldc)
{
    const int tid = threadIdx.x;
    const int wave = tid >> 6, lane = tid & 63;
    const int quad = lane >> 4, l15 = lane & 15;
    const int colbase = (blockIdx.x * NT) << 4;
    const int row = (blockIdx.y << 6) + (wave << 4) + l15;
    const size_t aoff = (size_t)row * lda;

    f32x4 acc0[NT], acc1[NT], acc2[NT];
    #pragma unroll
    for (int nt = 0; nt < NT; nt++) {
        acc0[nt] = {0.f,0.f,0.f,0.f}; acc1[nt] = acc0[nt]; acc2[nt] = acc0[nt];
    }
    size_t woff[NT];
    #pragma unroll
    for (int nt = 0; nt < NT; nt++)
        woff[nt] = (size_t)(colbase + (nt << 4) + l15) * K;

    #pragma unroll 2
    for (int kc = 0; kc < K; kc += 32) {
        const int ko = kc + quad * 8;
        const bf16x8 ah = APANEL ? ld8p(Ahi, row, ko) : ld8(Ahi + aoff + ko);
        bf16x8 al;
        if (A_LO) al = APANEL ? ld8p(Alo, row, ko) : ld8(Alo + aoff + ko);
        #pragma unroll
        for (int nt = 0; nt < NT; nt++) {
            const bf16x8 bh = ld8(Whi + woff[nt] + ko);
            const bf16x8 bl = ld8(Wlo + woff[nt] + ko);
            acc0[nt] = mfma16(ah, bh, acc0[nt]);
            acc1[nt] = mfma16(ah, bl, acc1[nt]);
            if (A_LO) acc2[nt] = mfma16(al, bh, acc2[nt]);
        }
    }
    const size_t orow0 = ((size_t)blockIdx.y << 6) + (wave << 4) + quad * 4;
    const size_t HALF_IDX = (size_t)32768 * 1024;   // P region boundary
    #pragma unroll
    for (int nt = 0; nt < NT; nt++) {
        const int col = colbase + (nt << 4) + l15;
        const float bv = bias ? bias[col] : 0.f;
        #pragma unroll
        for (int r = 0; r < 4; r++) {
            float v = acc0[nt][r] + acc1[nt][r] + (A_LO ? acc2[nt][r] : 0.f) + bv;
            if (RELU) v = fmaxf(v, 0.f);
            const size_t idx = (orow0 + r) * (size_t)ldc + col;
            if constexpr (OM == 0) {
                ((float*)out0)[idx] = v;
            } else if constexpr (OM == 3) {     // panel bf16 hi/lo
                const size_t idxp = ((size_t)(col >> 2) * B_ + (orow0 + r)) * 4 + (col & 3);
                const ushort h = f2bf(v);
                ((ushort*)out0)[idxp] = h;
                ((ushort*)out1)[idxp] = f2bf(v - bf2f(h));
            } else {   // OM == 4: fp16 dual region, row-major
                if (idx < HALF_IDX) ((_Float16*)out0)[idx] = (_Float16)v;
                else                ((_Float16*)out1)[idx - HALF_IDX] = (_Float16)v;
            }
        }
    }
}

// ---- scores[b][t] = sum_h v[h]*tanh(q[b][h] + P[t][b][h]); P fp16 2-region -
__global__ __launch_bounds__(256) void attn_score_kernel(
    const float* __restrict__ q,
    const _Float16* __restrict__ P0, const _Float16* __restrict__ P1,
    const float* __restrict__ v, float* __restrict__ scores)
{
    const int wave = threadIdx.x >> 6, lane = threadIdx.x & 63;
    const int p = (blockIdx.x << 2) + wave;
    const int t = p >> 7, b = p & 127;
    const size_t base = (size_t)(t * B_ + b) * H_ + (lane << 4);
    const size_t HALF_IDX = (size_t)32768 * 1024;
    const _Float16* pp = (base < HALF_IDX) ? (P0 + base) : (P1 + (base - HALF_IDX));

    const half8 u0 = *(const half8*)(const void*)pp;
    const half8 u1 = *(const half8*)(const void*)(pp + 8);
    float pv[16];
    #pragma unroll
    for (int j = 0; j < 8; j++) { pv[j] = (float)u0[j]; pv[8 + j] = (float)u1[j]; }

    const float* qp = q + b * H_ + (lane << 4);
    const float* vp = v + (lane << 4);
    float sum = 0.f;
    #pragma unroll
    for (int j0 = 0; j0 < 16; j0 += 4) {
        const float4 qv = *(const float4*)(qp + j0);
        const float4 vv = *(const float4*)(vp + j0);
        sum += vv.x * fast_tanh(qv.x + pv[j0 + 0]);
        sum += vv.y * fast_tanh(qv.y + pv[j0 + 1]);
        sum += vv.z * fast_tanh(qv.z + pv[j0 + 2]);
        sum += vv.w * fast_tanh(qv.w + pv[j0 + 3]);
    }
    #pragma unroll
    for (int off = 32; off; off >>= 1) sum += __shfl_down(sum, off);
    if (lane == 0) scores[b * T_ + t] = sum;
}

// ---- softmax over t; reads scores[b][t], writes transposed scT[t][b] -------
__global__ __launch_bounds__(256) void softmax_kernel(
    const float* __restrict__ scores, float* __restrict__ scT)
{
    __shared__ float red[256];
    const int b = blockIdx.x, tid = threadIdx.x;
    const float s0 = scores[b * T_ + tid];
    const float s1 = scores[b * T_ + tid + 256];
    red[tid] = fmaxf(s0, s1);
    __syncthreads();
    for (int off = 128; off; off >>= 1) {
        if (tid < off) red[tid] = fmaxf(red[tid], red[tid + off]);
        __syncthreads();
    }
    const float mx = red[0];
    __syncthreads();
    const float e0 = __expf(s0 - mx), e1 = __expf(s1 - mx);
    red[tid] = e0 + e1;
    __syncthreads();
    for (int off = 128; off; off >>= 1) {
        if (tid < off) red[tid] += red[tid + off];
        __syncthreads();
    }
    const float inv = 1.f / red[0];
    scT[tid * B_ + b] = e0 * inv;
    scT[(tid + 256) * B_ + b] = e1 * inv;
}

// ---- context partial: pctx[(cb*2+half)] = sum_{t in half} scT[t][b]*ctx ----
// grid 256 blocks x 256 thr = 65536; cb = (c,b); spreads BW over all CUs.
__global__ __launch_bounds__(256) void attn_context_part(
    const float* __restrict__ scT, const ushort* __restrict__ ctx,
    float* __restrict__ pctx)
{
    const int u = blockIdx.x * 256 + threadIdx.x;
    const int cb = u & 32767;
    const int half = u >> 15;
    const int c = cb >> 7, b = cb & 127;
    const ushort* cp = ctx + ((size_t)(c * B_ + b) << 2)
                           + (size_t)(half << 8) * (B_ * H_);
    const float* wp = scT + ((half << 8) * B_) + b;
    float a0 = 0.f, a1 = 0.f, a2 = 0.f, a3 = 0.f;
    #pragma unroll 4
    for (int t = 0; t < 256; t++) {
        const float w = wp[t << 7];
        const u64 raw = *(const u64*)(const void*)(cp + (size_t)t * (B_ * H_));
        a0 += w * bf2f((ushort)raw);
        a1 += w * bf2f((ushort)(raw >> 16));
        a2 += w * bf2f((ushort)(raw >> 32));
        a3 += w * bf2f((ushort)(raw >> 48));
    }
    float4 o = {a0, a1, a2, a3};
    *(float4*)(void*)(pctx + ((size_t)(cb << 1) + half) * 4) = o;
}

// ---- context finalize: add halves, split to panel bf16 hi/lo ---------------
__global__ __launch_bounds__(256) void attn_context_fin(
    const float* __restrict__ pctx,
    ushort* __restrict__ chi, ushort* __restrict__ clo)
{
    const int cb = blockIdx.x * 256 + threadIdx.x;   // 32768
    const float4 x0 = *(const float4*)(pctx + (size_t)cb * 8);
    const float4 x1 = *(const float4*)(pctx + (size_t)cb * 8 + 4);
    const float a0 = x0.x + x1.x, a1 = x0.y + x1.y;
    const float a2 = x0.z + x1.z, a3 = x0.w + x1.w;
    const size_t i0 = (size_t)cb << 2;
    const ushort h0 = f2bf(a0), h1 = f2bf(a1), h2 = f2bf(a2), h3 = f2bf(a3);
    const ushort l0 = f2bf(a0 - bf2f(h0)), l1 = f2bf(a1 - bf2f(h1));
    const ushort l2 = f2bf(a2 - bf2f(h2)), l3 = f2bf(a3 - bf2f(h3));
    *(u64*)(void*)&chi[i0] = (u64)h0 | ((u64)h1 << 16) | ((u64)h2 << 32) | ((u64)h3 << 48);
    *(u64*)(void*)&clo[i0] = (u64)l0 | ((u64)l1 << 16) | ((u64)l2 << 32) | ((u64)l3 << 48);
}

// ---------------------------------------------------------------------------
extern "C" void kernel_launch(void* const* d_in, const int* in_sizes, int n_in,
                              void* d_out, int out_size, void* d_ws, size_t ws_size,
                              hipStream_t stream)
{
    const float* input_seq = (const float*)d_in[0];
    const float* W_ih_enc  = (const float*)d_in[1];
    const float* W_hh_enc  = (const float*)d_in[2];
    const float* b_ih_enc  = (const float*)d_in[3];
    const float* b_hh_enc  = (const float*)d_in[4];
    const float* W_attn    = (const float*)d_in[5];
    const float* b_attn    = (const float*)d_in[6];
    const float* v         = (const float*)d_in[7];
    const float* W_ih_dec  = (const float*)d_in[8];
    const float* W_hh_dec  = (const float*)d_in[9];
    const float* b_ih_dec  = (const float*)d_in[10];
    const float* b_hh_dec  = (const float*)d_in[11];
    const float* W_dec     = (const float*)d_in[12];
    const float* b_dec     = (const float*)d_in[13];
    const float* W_out     = (const float*)d_in[14];
    const float* b_out     = (const float*)d_in[15];
    float* out = (float*)d_out;
    const int LEN = out_size / (B_ * O_);   // 30
    const int BH = B_ * H_;

    char* ws = (char*)d_ws;
    size_t off = 0;
    auto aus = [&](size_t n) { ushort* p = (ushort*)(ws + off); off += n * 2; return p; };
    auto af  = [&](size_t n) { float*  p = (float*) (ws + off); off += n * 4; return p; };

    // pre-split weights (hot / MFMA-consumed). Decoder LSTM W packed in place.
    ushort* WhhE_h = aus((size_t)4*H_*H_); ushort* WhhE_l = aus((size_t)4*H_*H_);
    ushort* WihE_h = aus((size_t)4*H_*I_); ushort* WihE_l = aus((size_t)4*H_*I_);
    ushort* Wh_h   = aus((size_t)H_*H_);   ushort* Wh_l   = aus((size_t)H_*H_);
    ushort* Wc_h   = aus((size_t)H_*H_);   ushort* Wc_l   = aus((size_t)H_*H_);
    ushort* Wdec_h = aus((size_t)H_*H_);   ushort* Wdec_l = aus((size_t)H_*H_);
    ushort* Wout_h = aus((size_t)O_*H_);   ushort* Wout_l = aus((size_t)O_*H_);

    ushort* ctx_seq = aus((size_t)T_ * BH);          // hi history, panel layout
    ushort* hzero   = aus(BH);
    ushort* enc_lo_fin = aus(BH);                    // final lo (post-P-GEMM use)
    ushort* hd_hi0  = aus(BH); ushort* hd_hi1  = aus(BH);
    ushort* hd_lo0  = aus(BH); ushort* hd_lo1  = aus(BH);
    ushort* ctx_hi  = aus(BH); ushort* ctx_lo  = aus(BH);
    ushort* d1_hi   = aus(BH); ushort* d1_lo   = aus(BH);
    float*  cbuf    = af(BH);
    float*  qbuf    = af(BH);
    float*  scores  = af(B_ * T_);
    float*  scT     = af(B_ * T_);
    float*  pctx    = af((size_t)32768 * 8);         // context partials (1 MB)
    unsigned* barbuf = (unsigned*)(ws + off); off += 4096;   // tree-barrier state

    // lo ring: 256 slots x 256KB = 67.1 MB. Dead after encoder -> P1 aliases it.
    ushort* loring = aus((size_t)LORING_SLOTS * BH);
    const size_t P_HALF = (size_t)(T_ / 2) * BH * 2;   // 67,108,864 == loring size
    _Float16* P1 = (_Float16*)loring;
    _Float16* P0;
    if (ws_size >= off + P_HALF) {            // spare ws for P0
        P0 = (_Float16*)(ws + off);
    } else {                                   // alias input_seq (dead after enc)
        P0 = (_Float16*)const_cast<float*>(input_seq);
    }

    // ---- weight split pre-pass ----
    auto spl = [&](const float* src, int srcld, int coloff, ushort* hi, ushort* lo,
                   int R, int K) {
        split_w<<<dim3(K / 256, R), 256, 0, stream>>>(src, srcld, coloff, hi, lo, K);
    };
    spl(W_hh_enc, H_,     0,  WhhE_h, WhhE_l, 4 * H_, H_);
    spl(W_ih_enc, I_,     0,  WihE_h, WihE_l, 4 * H_, I_);
    spl(W_attn,   2 * H_, 0,  Wh_h,   Wh_l,   H_,     H_);
    spl(W_attn,   2 * H_, H_, Wc_h,   Wc_l,   H_,     H_);
    spl(W_dec,    H_,     0,  Wdec_h, Wdec_l, H_,     H_);
    spl(W_out,    H_,     0,  Wout_h, Wout_l, O_,     H_);

    // ---- in-place packs: fp32 -> (bf16hi | bf16lo<<16) ----
    pack_x<<<(T_ * B_ * I_) / (256 * 8), 256, 0, stream>>>(
        const_cast<float*>(input_seq));
    pack_x<<<(4 * H_ * H_) / (256 * 8), 256, 0, stream>>>(
        const_cast<float*>(W_hh_dec));
    pack_x<<<(4 * H_ * H_) / (256 * 8), 256, 0, stream>>>(
        const_cast<float*>(W_ih_dec));

    hipMemsetAsync(hzero,  0, (size_t)BH * 2, stream);   // h_{-1} = lo_{-1} = 0
    hipMemsetAsync(barbuf, 0, 4096, stream);

    // ---- encoder: ONE persistent kernel, 512 steps, 64r x 32c blocks ----
    enc_persistent<<<dim3(H_ / 4), 1024, ENC_SMEM_BYTES, stream>>>(
        (const unsigned*)input_seq, WhhE_h, WhhE_l, WihE_h, WihE_l,
        b_ih_enc, b_hh_enc, hzero, ctx_seq, loring, enc_lo_fin, barbuf);
    // enc final: hi = ctx_seq[511] (panel), lo = enc_lo_fin (panel)

    // ---- P = ctx_seq @ W_c^T + b_attn  (fp16 row-major, dual region;
    //      P1 overwrites loring, P0 may overwrite input_seq — both dead) ----
    gemm_mfma<false, 8, 4, false, H_, true><<<dim3(8, (T_ * B_) / 64), 256, 0, stream>>>(
        ctx_seq, nullptr, H_, Wc_h, Wc_l, b_attn, P0, P1, H_);

    // ---- decoder ----
    hipMemsetAsync(cbuf, 0, (size_t)BH * 4, stream);
    ushort* dhh[2] = {hd_hi0, hd_hi1};
    ushort* dhl[2] = {hd_lo0, hd_lo1};
    for (int s = 0; s < LEN; s++) {
        const ushort* hi_in = (s == 0) ? ctx_seq + (size_t)(T_ - 1) * BH : dhh[s & 1];
        const ushort* lo_in = (s == 0) ? enc_lo_fin : dhl[s & 1];

        // q = h @ W_h^T (bias folded into P)
        gemm_mfma<true, 1, 0, false, H_, true><<<dim3(H_ / 16, 2), 256, 0, stream>>>(
            hi_in, lo_in, H_, Wh_h, Wh_l, nullptr, qbuf, nullptr, H_);
        attn_score_kernel<<<T_ * B_ / 4, 256, 0, stream>>>(qbuf, P0, P1, v, scores);
        softmax_kernel<<<B_, 256, 0, stream>>>(scores, scT);
        attn_context_part<<<256, 256, 0, stream>>>(scT, ctx_seq, pctx);
        attn_context_fin<<<128, 256, 0, stream>>>(pctx, ctx_hi, ctx_lo);
        // decoder LSTM cell (x = context panel; weights packed in place)
        lstm_mfma<true, true, H_><<<dim3(H_ / 4, 2), 256, 0, stream>>>(
            hi_in, lo_in, (const void*)ctx_hi, ctx_lo,
            (const void*)W_hh_dec, (const void*)W_ih_dec,
            b_ih_dec, b_hh_dec,
            cbuf, cbuf, dhh[(s + 1) & 1], dhl[(s + 1) & 1]);
        // d1 = relu(h @ W_dec^T + b_dec) -> split (panel out)
        gemm_mfma<true, 1, 3, true, H_, true><<<dim3(H_ / 16, 2), 256, 0, stream>>>(
            dhh[(s + 1) & 1], dhl[(s + 1) & 1], H_, Wdec_h, Wdec_l, b_dec,
            d1_hi, d1_lo, H_);
        // out = d1 @ W_out^T + b_out  (fp32 row-major final output)
        gemm_mfma<true, 1, 0, false, H_, true><<<dim3(O_ / 16, 2), 256, 0, stream>>>(
            d1_hi, d1_lo, H_, Wout_h, Wout_l, b_out,
            out + (size_t)s * B_ * O_, nullptr, O_);
    }
    (void)in_sizes; (void)n_in;
}